// Round 5
// baseline (515.353 us; speedup 1.0000x reference)
//
#include <hip/hip_runtime.h>
#include <hip/hip_bf16.h>

// Problem constants (fixed by the reference).
constexpr int N_NODES = 100000;
constexpr int N_EDGES = 1600000;
constexpr int IN_C  = 128;
constexpr int HID_C = 64;   // == OUT_C
constexpr int NUM_CLASSES = 40;

constexpr int SCAN_B = 256;
constexpr int NBLK = (N_NODES + SCAN_B - 1) / SCAN_B;   // 391

// ---------------------------------------------------------------- degree ----
__global__ void deg_count_kernel(const int* __restrict__ dst, unsigned* __restrict__ deg) {
    int e = blockIdx.x * blockDim.x + threadIdx.x;
    if (e < N_EDGES) atomicAdd(&deg[dst[e]], 1u);
}

// ------------------------------------------------- parallel 3-phase scan ----
// Phase 1: per-block sums of deg (391 blocks x 256).
__global__ __launch_bounds__(SCAN_B) void block_sum_kernel(
        const unsigned* __restrict__ deg, unsigned* __restrict__ partials) {
    __shared__ unsigned s[SCAN_B];
    int t = threadIdx.x;
    int i = blockIdx.x * SCAN_B + t;
    s[t] = (i < N_NODES) ? deg[i] : 0u;
    __syncthreads();
    for (int off = SCAN_B / 2; off > 0; off >>= 1) {
        if (t < off) s[t] += s[t + off];
        __syncthreads();
    }
    if (t == 0) partials[blockIdx.x] = s[0];
}

// Phase 2: single block scans the 391 partials (exclusive); writes rowptr[N].
__global__ __launch_bounds__(512) void scan_partials_kernel(
        unsigned* __restrict__ partials, unsigned* __restrict__ rowptr) {
    __shared__ unsigned s[512];
    int t = threadIdx.x;
    unsigned v = (t < NBLK) ? partials[t] : 0u;
    s[t] = v;
    __syncthreads();
    for (int off = 1; off < 512; off <<= 1) {
        unsigned u = (t >= off) ? s[t - off] : 0u;
        __syncthreads();
        s[t] += u;
        __syncthreads();
    }
    if (t < NBLK) partials[t] = s[t] - v;          // exclusive prefix
    if (t == NBLK - 1) rowptr[N_NODES] = s[t];     // total edge count
}

// Phase 3: in-block exclusive scan + block base; writes rowptr, cursor, inv.
__global__ __launch_bounds__(SCAN_B) void scan_final_kernel(
        unsigned* __restrict__ deg, const unsigned* __restrict__ partials,
        unsigned* __restrict__ rowptr, float* __restrict__ inv) {
    __shared__ unsigned s[SCAN_B];
    int t = threadIdx.x;
    int i = blockIdx.x * SCAN_B + t;
    unsigned d = (i < N_NODES) ? deg[i] : 0u;
    s[t] = d;
    __syncthreads();
    for (int off = 1; off < SCAN_B; off <<= 1) {
        unsigned u = (t >= off) ? s[t - off] : 0u;
        __syncthreads();
        s[t] += u;
        __syncthreads();
    }
    if (i < N_NODES) {
        unsigned pos = partials[blockIdx.x] + s[t] - d;   // exclusive
        rowptr[i] = pos;
        deg[i]    = pos;                        // fill cursor
        inv[i]    = rsqrtf((float)(d + 1u));    // +1 self-loop
    }
}

// Scattered 4B plain stores cost a 64B line eviction each (measured R4:
// WRITE_SIZE 106 MB for a 6.4 MB payload). Atomics write through at payload
// granularity (measured R2: exactly 4 B/atomic). So scatter via atomicExch.
__global__ void fill_kernel(const int* __restrict__ src, const int* __restrict__ dst,
                            unsigned* __restrict__ cursor, unsigned* __restrict__ csr_src) {
    int e = blockIdx.x * blockDim.x + threadIdx.x;
    if (e >= N_EDGES) return;
    unsigned pos = atomicAdd(&cursor[dst[e]], 1u);
    atomicExch(&csr_src[pos], (unsigned)src[e]);
}

// -------------------------------------------------- GEMM (X@W)*inv -> out ---
// X: [n, K] f32 row-major, W: [K, 64] f32 row-major, out[nn] = (X@W)[nn]*inv[nn].
// Block: 256 threads, tile 64 rows x 64 cols, each thread 4x4 outputs.
template <int K>
__global__ __launch_bounds__(256) void gemm_scale_kernel(
        const float* __restrict__ X, const float* __restrict__ W,
        const float* __restrict__ inv, float* __restrict__ out, int n) {
    constexpr int C = 64;
    __shared__ float Ws[K * C];
    __shared__ float Xs[64][68];   // [k in chunk][row]; stride 68 keeps 16B align
    int t = threadIdx.x;
    int n0 = blockIdx.x * 64;
    for (int i = t; i < K * C / 4; i += 256)
        ((float4*)Ws)[i] = ((const float4*)W)[i];
    int cg = t & 15;          // col group: cols cg*4..+3
    int rg = t >> 4;          // row group: rows rg*4..+3
    float4 a0 = {0,0,0,0}, a1 = {0,0,0,0}, a2 = {0,0,0,0}, a3 = {0,0,0,0};
    for (int kb = 0; kb < K; kb += 64) {
        __syncthreads();
        for (int i = t; i < 1024; i += 256) {     // 64 rows x 16 float4
            int row = i >> 4, kc = i & 15;
            int nn = n0 + row;
            float4 v = {0,0,0,0};
            if (nn < n) v = *(const float4*)&X[(size_t)nn * K + kb + kc * 4];
            Xs[kc * 4 + 0][row] = v.x;
            Xs[kc * 4 + 1][row] = v.y;
            Xs[kc * 4 + 2][row] = v.z;
            Xs[kc * 4 + 3][row] = v.w;
        }
        __syncthreads();
#pragma unroll 8
        for (int k = 0; k < 64; ++k) {
            float4 b = *(const float4*)&Ws[(kb + k) * C + cg * 4];
            float4 a = *(const float4*)&Xs[k][rg * 4];
            a0.x += a.x * b.x; a0.y += a.x * b.y; a0.z += a.x * b.z; a0.w += a.x * b.w;
            a1.x += a.y * b.x; a1.y += a.y * b.y; a1.z += a.y * b.z; a1.w += a.y * b.w;
            a2.x += a.z * b.x; a2.y += a.z * b.y; a2.z += a.z * b.z; a2.w += a.z * b.w;
            a3.x += a.w * b.x; a3.y += a.w * b.y; a3.z += a.w * b.z; a3.w += a.w * b.w;
        }
    }
    float4 accs[4] = {a0, a1, a2, a3};
#pragma unroll
    for (int i = 0; i < 4; ++i) {
        int nn = n0 + rg * 4 + i;
        if (nn < n) {
            float s = inv[nn];
            float4 r = accs[i];
            r.x *= s; r.y *= s; r.z *= s; r.w *= s;
            *(float4*)&out[(size_t)nn * C + cg * 4] = r;
        }
    }
}

// ---------------------------------------- fused gather-aggregate + epilogue -
// One wave per node: out[d] = relu(inv[d] * (sum_{s in N(d)} hs[s] + hs[d]) + b)
__global__ __launch_bounds__(256) void agg_fused_kernel(
        const unsigned* __restrict__ rowptr, const unsigned* __restrict__ csr_src,
        const float* __restrict__ hs, const float* __restrict__ inv,
        const float* __restrict__ bias, float* __restrict__ out) {
    int node = blockIdx.x * 4 + (threadIdx.x >> 6);
    int lane = threadIdx.x & 63;
    int q  = lane >> 4;
    int cl = lane & 15;
    unsigned beg = rowptr[node], end = rowptr[node + 1];
    float ax = 0.f, ay = 0.f, az = 0.f, aw = 0.f;
    for (unsigned j = beg + q; j < end; j += 4) {
        unsigned s = csr_src[j];
        const float4 v = *(const float4*)&hs[(size_t)s * 64 + cl * 4];
        ax += v.x; ay += v.y; az += v.z; aw += v.w;
    }
    ax += __shfl_xor(ax, 16); ay += __shfl_xor(ay, 16);
    az += __shfl_xor(az, 16); aw += __shfl_xor(aw, 16);
    ax += __shfl_xor(ax, 32); ay += __shfl_xor(ay, 32);
    az += __shfl_xor(az, 32); aw += __shfl_xor(aw, 32);
    if (q == 0) {
        const float4 self = *(const float4*)&hs[(size_t)node * 64 + cl * 4];
        const float4 bv   = *(const float4*)&bias[cl * 4];
        float s = inv[node];
        float4 r;
        r.x = fmaxf(s * (ax + self.x) + bv.x, 0.f);
        r.y = fmaxf(s * (ay + self.y) + bv.y, 0.f);
        r.z = fmaxf(s * (az + self.z) + bv.z, 0.f);
        r.w = fmaxf(s * (aw + self.w) + bv.w, 0.f);
        *(float4*)&out[(size_t)node * 64 + cl * 4] = r;
    }
}

// ---------------------------------------------- final classifier GEMM -------
// out[n, 40] = H[n, 64] @ Wf[64, 40] + bf.  Block 320, tile 128 rows x 40 cols.
__global__ __launch_bounds__(320) void final_gemm_kernel(
        const float* __restrict__ H, const float* __restrict__ Wf,
        const float* __restrict__ bfv, float* __restrict__ out, int n) {
    constexpr int CK = 64, J = 40;
    __shared__ float Ws[CK * J];
    __shared__ float Hs[CK][132];   // [k][row 0..127], stride 132 (16B align)
    int t = threadIdx.x;
    int n0 = blockIdx.x * 128;
    for (int i = t; i < CK * J / 4; i += 320)
        ((float4*)Ws)[i] = ((const float4*)Wf)[i];
    for (int i = t; i < 128 * 16; i += 320) {   // 128 rows x 16 float4
        int row = i >> 4, kc = i & 15;
        int nn = n0 + row;
        float4 v = {0,0,0,0};
        if (nn < n) v = *(const float4*)&H[(size_t)nn * 64 + kc * 4];
        Hs[kc * 4 + 0][row] = v.x;
        Hs[kc * 4 + 1][row] = v.y;
        Hs[kc * 4 + 2][row] = v.z;
        Hs[kc * 4 + 3][row] = v.w;
    }
    __syncthreads();
    int cg = t % 10;          // cols cg*4..+3 (of 40)
    int rg = t / 10;          // rows rg*4..+3 (0..31 -> 128 rows)
    float4 a0 = {0,0,0,0}, a1 = {0,0,0,0}, a2 = {0,0,0,0}, a3 = {0,0,0,0};
#pragma unroll 8
    for (int k = 0; k < CK; ++k) {
        float4 b = *(const float4*)&Ws[k * J + cg * 4];
        float4 a = *(const float4*)&Hs[k][rg * 4];
        a0.x += a.x * b.x; a0.y += a.x * b.y; a0.z += a.x * b.z; a0.w += a.x * b.w;
        a1.x += a.y * b.x; a1.y += a.y * b.y; a1.z += a.y * b.z; a1.w += a.y * b.w;
        a2.x += a.z * b.x; a2.y += a.z * b.y; a2.z += a.z * b.z; a2.w += a.z * b.w;
        a3.x += a.w * b.x; a3.y += a.w * b.y; a3.z += a.w * b.z; a3.w += a.w * b.w;
    }
    float4 bv = *(const float4*)&bfv[cg * 4];
    float4 accs[4] = {a0, a1, a2, a3};
#pragma unroll
    for (int i = 0; i < 4; ++i) {
        int nn = n0 + rg * 4 + i;
        if (nn < n) {
            float4 r = accs[i];
            r.x += bv.x; r.y += bv.y; r.z += bv.z; r.w += bv.w;
            *(float4*)&out[(size_t)nn * J + cg * 4] = r;
        }
    }
}

// ---------------------------------------------------------------- launch ----
extern "C" void kernel_launch(void* const* d_in, const int* in_sizes, int n_in,
                              void* d_out, int out_size, void* d_ws, size_t ws_size,
                              hipStream_t stream) {
    const float* x  = (const float*)d_in[0];
    const int*   ei = (const int*)d_in[1];
    const float* W1 = (const float*)d_in[2];
    const float* b1 = (const float*)d_in[3];
    const float* W2 = (const float*)d_in[4];
    const float* b2 = (const float*)d_in[5];
    const float* Wf = (const float*)d_in[6];
    const float* bf = (const float*)d_in[7];
    float* out = (float*)d_out;

    const int* src = ei;            // edge_index[0, :]
    const int* dst = ei + N_EDGES;  // edge_index[1, :]

    // Workspace layout (bytes):
    // deg/cursor: [0, 400000) | rowptr: [400000, 800004) | inv: [800064, 1200064)
    // partials: [1200064, 1201628) | csr_src: [1201664, 7601664)
    // A: [7601664, +25.6M) | B: [33201664, +25.6M)
    char* ws = (char*)d_ws;
    unsigned* deg      = (unsigned*)(ws + 0);
    unsigned* rowptr   = (unsigned*)(ws + 400000);
    float*    inv      = (float*)   (ws + 800064);
    unsigned* partials = (unsigned*)(ws + 1200064);
    unsigned* csr_src  = (unsigned*)(ws + 1201664);
    float*    A        = (float*)   (ws + 7601664);
    float*    B        = (float*)   (ws + 33201664);

    const int T = 256;
    const int EB = (N_EDGES + T - 1) / T;

    // ---- CSR build (per-call; no state may survive between calls)
    hipMemsetAsync(deg, 0, N_NODES * sizeof(unsigned), stream);
    deg_count_kernel<<<EB, T, 0, stream>>>(dst, deg);
    block_sum_kernel<<<NBLK, SCAN_B, 0, stream>>>(deg, partials);
    scan_partials_kernel<<<1, 512, 0, stream>>>(partials, rowptr);
    scan_final_kernel<<<NBLK, SCAN_B, 0, stream>>>(deg, partials, rowptr, inv);
    fill_kernel<<<EB, T, 0, stream>>>(src, dst, deg, csr_src);

    // ---- Layer 1
    gemm_scale_kernel<IN_C><<<(N_NODES + 63) / 64, 256, 0, stream>>>(x, W1, inv, A, N_NODES);
    agg_fused_kernel<<<N_NODES / 4, 256, 0, stream>>>(rowptr, csr_src, A, inv, b1, B);

    // ---- Layer 2
    gemm_scale_kernel<HID_C><<<(N_NODES + 63) / 64, 256, 0, stream>>>(B, W2, inv, A, N_NODES);
    agg_fused_kernel<<<N_NODES / 4, 256, 0, stream>>>(rowptr, csr_src, A, inv, b2, B);

    // ---- Classifier
    final_gemm_kernel<<<(N_NODES + 127) / 128, 320, 0, stream>>>(B, Wf, bf, out, N_NODES);
}

// Round 6
// 410.992 us; speedup vs baseline: 1.2539x; 1.2539x over previous
//
#include <hip/hip_runtime.h>
#include <hip/hip_bf16.h>

// Problem constants (fixed by the reference).
constexpr int N_NODES = 100000;
constexpr int N_EDGES = 1600000;
constexpr int IN_C  = 128;
constexpr int HID_C = 64;   // == OUT_C
constexpr int NUM_CLASSES = 40;

constexpr int SCAN_B = 256;
constexpr int NBLK = (N_NODES + SCAN_B - 1) / SCAN_B;   // 391

// Bucketed CSR build: 512-node buckets.
constexpr int BSH = 9;
constexpr int BUCK_N = 1 << BSH;                          // 512
constexpr int NBUCK = (N_NODES + BUCK_N - 1) >> BSH;      // 196
constexpr int FS_EPT = 16;                                // edges/thread
constexpr int FS_T = 256;
constexpr int FS_CHUNK = FS_EPT * FS_T;                   // 4096
constexpr int FS_BLKS = (N_EDGES + FS_CHUNK - 1) / FS_CHUNK;  // 391
constexpr int FF_CAP = 11264;   // 44 KB LDS; mean bucket 8163 edges, sigma~90

// ---------------------------------------------------------------- degree ----
__global__ void deg_count_kernel(const int* __restrict__ dst, unsigned* __restrict__ deg) {
    int e = blockIdx.x * blockDim.x + threadIdx.x;
    if (e < N_EDGES) atomicAdd(&deg[dst[e]], 1u);
}

// ------------------------------------------------- parallel 3-phase scan ----
__global__ __launch_bounds__(SCAN_B) void block_sum_kernel(
        const unsigned* __restrict__ deg, unsigned* __restrict__ partials) {
    __shared__ unsigned s[SCAN_B];
    int t = threadIdx.x;
    int i = blockIdx.x * SCAN_B + t;
    s[t] = (i < N_NODES) ? deg[i] : 0u;
    __syncthreads();
    for (int off = SCAN_B / 2; off > 0; off >>= 1) {
        if (t < off) s[t] += s[t + off];
        __syncthreads();
    }
    if (t == 0) partials[blockIdx.x] = s[0];
}

__global__ __launch_bounds__(512) void scan_partials_kernel(
        unsigned* __restrict__ partials, unsigned* __restrict__ rowptr) {
    __shared__ unsigned s[512];
    int t = threadIdx.x;
    unsigned v = (t < NBLK) ? partials[t] : 0u;
    s[t] = v;
    __syncthreads();
    for (int off = 1; off < 512; off <<= 1) {
        unsigned u = (t >= off) ? s[t - off] : 0u;
        __syncthreads();
        s[t] += u;
        __syncthreads();
    }
    if (t < NBLK) partials[t] = s[t] - v;          // exclusive prefix
    if (t == NBLK - 1) rowptr[N_NODES] = s[t];     // total edge count
}

__global__ __launch_bounds__(SCAN_B) void scan_final_kernel(
        const unsigned* __restrict__ deg, const unsigned* __restrict__ partials,
        unsigned* __restrict__ rowptr, float* __restrict__ inv) {
    __shared__ unsigned s[SCAN_B];
    int t = threadIdx.x;
    int i = blockIdx.x * SCAN_B + t;
    unsigned d = (i < N_NODES) ? deg[i] : 0u;
    s[t] = d;
    __syncthreads();
    for (int off = 1; off < SCAN_B; off <<= 1) {
        unsigned u = (t >= off) ? s[t - off] : 0u;
        __syncthreads();
        s[t] += u;
        __syncthreads();
    }
    if (i < N_NODES) {
        rowptr[i] = partials[blockIdx.x] + s[t] - d;   // exclusive
        inv[i]    = rsqrtf((float)(d + 1u));           // +1 self-loop
    }
}

// gcur[b] = staging/CSR base of bucket b.
__global__ void bucket_init_kernel(const unsigned* __restrict__ rowptr,
                                   unsigned* __restrict__ gcur) {
    int b = blockIdx.x * blockDim.x + threadIdx.x;
    if (b < NBUCK) gcur[b] = rowptr[b << BSH];
}

// Phase 1 of fill: group edges by 512-node bucket into `stage`, packed
// (src<<9)|dst_lo. Each (block,bucket) run is contiguous and written from one
// CU => dense dirty lines (the R4/R5 scatter wrote 64B/line for 4B payload).
__global__ __launch_bounds__(FS_T) void fill_stage_kernel(
        const int* __restrict__ src, const int* __restrict__ dst,
        unsigned* __restrict__ gcur, unsigned* __restrict__ stage) {
    __shared__ unsigned hist[NBUCK];
    __shared__ unsigned rbase[NBUCK];
    int t = threadIdx.x;
    for (int i = t; i < NBUCK; i += FS_T) hist[i] = 0u;
    __syncthreads();
    int e0 = blockIdx.x * FS_CHUNK + t;
    unsigned pay[FS_EPT];
    unsigned br[FS_EPT];   // (bucket<<16)|rank, 0xFFFFFFFF = invalid
#pragma unroll
    for (int i = 0; i < FS_EPT; ++i) {
        int e = e0 + i * FS_T;
        br[i] = 0xFFFFFFFFu; pay[i] = 0u;
        if (e < N_EDGES) {
            unsigned d = (unsigned)dst[e];
            unsigned s = (unsigned)src[e];
            unsigned b = d >> BSH;
            unsigned r = atomicAdd(&hist[b], 1u);   // rank < 4096
            pay[i] = (s << BSH) | (d & (BUCK_N - 1u));
            br[i]  = (b << 16) | r;
        }
    }
    __syncthreads();
    for (int i = t; i < NBUCK; i += FS_T) {
        unsigned c = hist[i];
        rbase[i] = c ? atomicAdd(&gcur[i], c) : 0u;
    }
    __syncthreads();
#pragma unroll
    for (int i = 0; i < FS_EPT; ++i) {
        if (br[i] != 0xFFFFFFFFu)
            stage[rbase[br[i] >> 16] + (br[i] & 0xFFFFu)] = pay[i];
    }
}

// Phase 2: one block per bucket. Assemble the bucket's CSR slice in LDS with
// LDS cursors, then copy out fully coalesced.
__global__ __launch_bounds__(256) void fill_final_kernel(
        const unsigned* __restrict__ rowptr, const unsigned* __restrict__ stage,
        unsigned* __restrict__ csr_src) {
    __shared__ unsigned cur[BUCK_N];
    __shared__ unsigned buf[FF_CAP];
    int b = blockIdx.x;
    int t = threadIdx.x;
    int lo = b << BSH;
    int hi = min(lo + BUCK_N, N_NODES);
    unsigned base = rowptr[lo];
    unsigned size = rowptr[hi] - base;
    for (int i = t; i < hi - lo; i += 256) cur[i] = rowptr[lo + i] - base;
    __syncthreads();
    if (size <= FF_CAP) {
        for (int i = t; i < (int)size; i += 256) {
            unsigned v = stage[base + i];
            unsigned pos = atomicAdd(&cur[v & (BUCK_N - 1u)], 1u);
            buf[pos] = v >> BSH;
        }
        __syncthreads();
        for (int i = t; i < (int)size; i += 256) csr_src[base + i] = buf[i];
    } else {   // statistically unreachable fallback (keeps correctness)
        for (int i = t; i < (int)size; i += 256) {
            unsigned v = stage[base + i];
            unsigned pos = atomicAdd(&cur[v & (BUCK_N - 1u)], 1u);
            csr_src[base + pos] = v >> BSH;
        }
    }
}

// -------------------------------------------------- GEMM (X@W)*inv -> out ---
template <int K>
__global__ __launch_bounds__(256) void gemm_scale_kernel(
        const float* __restrict__ X, const float* __restrict__ W,
        const float* __restrict__ inv, float* __restrict__ out, int n) {
    constexpr int C = 64;
    __shared__ float Ws[K * C];
    __shared__ float Xs[64][68];
    int t = threadIdx.x;
    int n0 = blockIdx.x * 64;
    for (int i = t; i < K * C / 4; i += 256)
        ((float4*)Ws)[i] = ((const float4*)W)[i];
    int cg = t & 15;
    int rg = t >> 4;
    float4 a0 = {0,0,0,0}, a1 = {0,0,0,0}, a2 = {0,0,0,0}, a3 = {0,0,0,0};
    for (int kb = 0; kb < K; kb += 64) {
        __syncthreads();
        for (int i = t; i < 1024; i += 256) {
            int row = i >> 4, kc = i & 15;
            int nn = n0 + row;
            float4 v = {0,0,0,0};
            if (nn < n) v = *(const float4*)&X[(size_t)nn * K + kb + kc * 4];
            Xs[kc * 4 + 0][row] = v.x;
            Xs[kc * 4 + 1][row] = v.y;
            Xs[kc * 4 + 2][row] = v.z;
            Xs[kc * 4 + 3][row] = v.w;
        }
        __syncthreads();
#pragma unroll 8
        for (int k = 0; k < 64; ++k) {
            float4 b = *(const float4*)&Ws[(kb + k) * C + cg * 4];
            float4 a = *(const float4*)&Xs[k][rg * 4];
            a0.x += a.x * b.x; a0.y += a.x * b.y; a0.z += a.x * b.z; a0.w += a.x * b.w;
            a1.x += a.y * b.x; a1.y += a.y * b.y; a1.z += a.y * b.z; a1.w += a.y * b.w;
            a2.x += a.z * b.x; a2.y += a.z * b.y; a2.z += a.z * b.z; a2.w += a.z * b.w;
            a3.x += a.w * b.x; a3.y += a.w * b.y; a3.z += a.w * b.z; a3.w += a.w * b.w;
        }
    }
    float4 accs[4] = {a0, a1, a2, a3};
#pragma unroll
    for (int i = 0; i < 4; ++i) {
        int nn = n0 + rg * 4 + i;
        if (nn < n) {
            float s = inv[nn];
            float4 r = accs[i];
            r.x *= s; r.y *= s; r.z *= s; r.w *= s;
            *(float4*)&out[(size_t)nn * C + cg * 4] = r;
        }
    }
}

// ---------------------------------------- fused gather-aggregate + epilogue -
__global__ __launch_bounds__(256) void agg_fused_kernel(
        const unsigned* __restrict__ rowptr, const unsigned* __restrict__ csr_src,
        const float* __restrict__ hs, const float* __restrict__ inv,
        const float* __restrict__ bias, float* __restrict__ out) {
    int node = blockIdx.x * 4 + (threadIdx.x >> 6);
    int lane = threadIdx.x & 63;
    int q  = lane >> 4;
    int cl = lane & 15;
    unsigned beg = rowptr[node], end = rowptr[node + 1];
    float ax = 0.f, ay = 0.f, az = 0.f, aw = 0.f;
    for (unsigned j = beg + q; j < end; j += 4) {
        unsigned s = csr_src[j];
        const float4 v = *(const float4*)&hs[(size_t)s * 64 + cl * 4];
        ax += v.x; ay += v.y; az += v.z; aw += v.w;
    }
    ax += __shfl_xor(ax, 16); ay += __shfl_xor(ay, 16);
    az += __shfl_xor(az, 16); aw += __shfl_xor(aw, 16);
    ax += __shfl_xor(ax, 32); ay += __shfl_xor(ay, 32);
    az += __shfl_xor(az, 32); aw += __shfl_xor(aw, 32);
    if (q == 0) {
        const float4 self = *(const float4*)&hs[(size_t)node * 64 + cl * 4];
        const float4 bv   = *(const float4*)&bias[cl * 4];
        float s = inv[node];
        float4 r;
        r.x = fmaxf(s * (ax + self.x) + bv.x, 0.f);
        r.y = fmaxf(s * (ay + self.y) + bv.y, 0.f);
        r.z = fmaxf(s * (az + self.z) + bv.z, 0.f);
        r.w = fmaxf(s * (aw + self.w) + bv.w, 0.f);
        *(float4*)&out[(size_t)node * 64 + cl * 4] = r;
    }
}

// ---------------------------------------------- final classifier GEMM -------
__global__ __launch_bounds__(320) void final_gemm_kernel(
        const float* __restrict__ H, const float* __restrict__ Wf,
        const float* __restrict__ bfv, float* __restrict__ out, int n) {
    constexpr int CK = 64, J = 40;
    __shared__ float Ws[CK * J];
    __shared__ float Hs[CK][132];
    int t = threadIdx.x;
    int n0 = blockIdx.x * 128;
    for (int i = t; i < CK * J / 4; i += 320)
        ((float4*)Ws)[i] = ((const float4*)Wf)[i];
    for (int i = t; i < 128 * 16; i += 320) {
        int row = i >> 4, kc = i & 15;
        int nn = n0 + row;
        float4 v = {0,0,0,0};
        if (nn < n) v = *(const float4*)&H[(size_t)nn * 64 + kc * 4];
        Hs[kc * 4 + 0][row] = v.x;
        Hs[kc * 4 + 1][row] = v.y;
        Hs[kc * 4 + 2][row] = v.z;
        Hs[kc * 4 + 3][row] = v.w;
    }
    __syncthreads();
    int cg = t % 10;
    int rg = t / 10;
    float4 a0 = {0,0,0,0}, a1 = {0,0,0,0}, a2 = {0,0,0,0}, a3 = {0,0,0,0};
#pragma unroll 8
    for (int k = 0; k < CK; ++k) {
        float4 b = *(const float4*)&Ws[k * J + cg * 4];
        float4 a = *(const float4*)&Hs[k][rg * 4];
        a0.x += a.x * b.x; a0.y += a.x * b.y; a0.z += a.x * b.z; a0.w += a.x * b.w;
        a1.x += a.y * b.x; a1.y += a.y * b.y; a1.z += a.y * b.z; a1.w += a.y * b.w;
        a2.x += a.z * b.x; a2.y += a.z * b.y; a2.z += a.z * b.z; a2.w += a.z * b.w;
        a3.x += a.w * b.x; a3.y += a.w * b.y; a3.z += a.w * b.z; a3.w += a.w * b.w;
    }
    float4 bv = *(const float4*)&bfv[cg * 4];
    float4 accs[4] = {a0, a1, a2, a3};
#pragma unroll
    for (int i = 0; i < 4; ++i) {
        int nn = n0 + rg * 4 + i;
        if (nn < n) {
            float4 r = accs[i];
            r.x += bv.x; r.y += bv.y; r.z += bv.z; r.w += bv.w;
            *(float4*)&out[(size_t)nn * J + cg * 4] = r;
        }
    }
}

// ---------------------------------------------------------------- launch ----
extern "C" void kernel_launch(void* const* d_in, const int* in_sizes, int n_in,
                              void* d_out, int out_size, void* d_ws, size_t ws_size,
                              hipStream_t stream) {
    const float* x  = (const float*)d_in[0];
    const int*   ei = (const int*)d_in[1];
    const float* W1 = (const float*)d_in[2];
    const float* b1 = (const float*)d_in[3];
    const float* W2 = (const float*)d_in[4];
    const float* b2 = (const float*)d_in[5];
    const float* Wf = (const float*)d_in[6];
    const float* bf = (const float*)d_in[7];
    float* out = (float*)d_out;

    const int* src = ei;            // edge_index[0, :]
    const int* dst = ei + N_EDGES;  // edge_index[1, :]

    // Workspace layout (bytes):
    // deg: [0, 400000) | rowptr: [400000, 800064) | inv: [800064, 1200064)
    // partials: [1200064, 1201664) | gcur: [1201664, 1202688)
    // csr_src: [1202688, 7602688) | A: [7603200, +25.6M) | B: [33203200, +25.6M)
    // stage (6.4 MB) aliases A: dead before gemm1 writes A (stream-ordered).
    char* ws = (char*)d_ws;
    unsigned* deg      = (unsigned*)(ws + 0);
    unsigned* rowptr   = (unsigned*)(ws + 400000);
    float*    inv      = (float*)   (ws + 800064);
    unsigned* partials = (unsigned*)(ws + 1200064);
    unsigned* gcur     = (unsigned*)(ws + 1201664);
    unsigned* csr_src  = (unsigned*)(ws + 1202688);
    float*    A        = (float*)   (ws + 7603200);
    float*    B        = (float*)   (ws + 33203200);
    unsigned* stage    = (unsigned*)A;

    const int T = 256;
    const int EB = (N_EDGES + T - 1) / T;

    // ---- CSR build (per-call; no state survives between calls)
    hipMemsetAsync(deg, 0, N_NODES * sizeof(unsigned), stream);
    deg_count_kernel<<<EB, T, 0, stream>>>(dst, deg);
    block_sum_kernel<<<NBLK, SCAN_B, 0, stream>>>(deg, partials);
    scan_partials_kernel<<<1, 512, 0, stream>>>(partials, rowptr);
    scan_final_kernel<<<NBLK, SCAN_B, 0, stream>>>(deg, partials, rowptr, inv);
    bucket_init_kernel<<<1, NBUCK, 0, stream>>>(rowptr, gcur);
    fill_stage_kernel<<<FS_BLKS, FS_T, 0, stream>>>(src, dst, gcur, stage);
    fill_final_kernel<<<NBUCK, 256, 0, stream>>>(rowptr, stage, csr_src);

    // ---- Layer 1
    gemm_scale_kernel<IN_C><<<(N_NODES + 63) / 64, 256, 0, stream>>>(x, W1, inv, A, N_NODES);
    agg_fused_kernel<<<N_NODES / 4, 256, 0, stream>>>(rowptr, csr_src, A, inv, b1, B);

    // ---- Layer 2
    gemm_scale_kernel<HID_C><<<(N_NODES + 63) / 64, 256, 0, stream>>>(B, W2, inv, A, N_NODES);
    agg_fused_kernel<<<N_NODES / 4, 256, 0, stream>>>(rowptr, csr_src, A, inv, b2, B);

    // ---- Classifier
    final_gemm_kernel<<<(N_NODES + 127) / 128, 320, 0, stream>>>(B, Wf, bf, out, N_NODES);
}

// Round 7
// 329.167 us; speedup vs baseline: 1.5656x; 1.2486x over previous
//
#include <hip/hip_runtime.h>

// Problem constants (fixed by the reference).
constexpr int N_NODES = 100000;
constexpr int N_EDGES = 1600000;
constexpr int IN_C  = 128;
constexpr int HID_C = 64;   // == OUT_C
constexpr int NUM_CLASSES = 40;

// Bucketed CSR build: 512-node buckets, fixed-capacity staging.
constexpr int BSH = 9;
constexpr int BUCK_N = 1 << BSH;                          // 512
constexpr int NBUCK = (N_NODES + BUCK_N - 1) >> BSH;      // 196
constexpr int BCAP = 9216;      // per-bucket cap; mean 8192, sd~90 (11σ margin)
constexpr int FS_EPT = 16;
constexpr int FS_T = 256;
constexpr int FS_CHUNK = FS_EPT * FS_T;                   // 4096
constexpr int FS_BLKS = (N_EDGES + FS_CHUNK - 1) / FS_CHUNK;  // 391

// bf16 storage helpers (fp32 math everywhere; bf16 only at rest).
__device__ __forceinline__ unsigned short f2bf(float f) {
    unsigned u = __float_as_uint(f);
    return (unsigned short)((u + 0x7FFFu + ((u >> 16) & 1u)) >> 16);   // RNE
}
__device__ __forceinline__ float bf2f(unsigned short h) {
    return __uint_as_float((unsigned)h << 16);
}

// ---------------------------------------------------------------- CSR -------
__global__ void bucket_init_kernel(unsigned* __restrict__ gcur) {
    if (threadIdx.x < NBUCK) gcur[threadIdx.x] = 0u;
}

// Group edges into fixed per-bucket staging regions, packed (src<<9)|dst_lo.
// Per-(block,bucket) runs are contiguous => line-dense writes (R4/R5 showed
// scattered 4B stores cost a full 64B line each).
__global__ __launch_bounds__(FS_T) void fill_stage_kernel(
        const int* __restrict__ src, const int* __restrict__ dst,
        unsigned* __restrict__ gcur, unsigned* __restrict__ stage) {
    __shared__ unsigned hist[NBUCK];
    __shared__ unsigned rbase[NBUCK];
    int t = threadIdx.x;
    for (int i = t; i < NBUCK; i += FS_T) hist[i] = 0u;
    __syncthreads();
    int e0 = blockIdx.x * FS_CHUNK + t;
    unsigned pay[FS_EPT];
    unsigned br[FS_EPT];   // (bucket<<16)|rank
#pragma unroll
    for (int i = 0; i < FS_EPT; ++i) {
        int e = e0 + i * FS_T;
        br[i] = 0xFFFFFFFFu; pay[i] = 0u;
        if (e < N_EDGES) {
            unsigned d = (unsigned)dst[e];
            unsigned s = (unsigned)src[e];
            unsigned b = d >> BSH;
            unsigned r = atomicAdd(&hist[b], 1u);   // rank < 4096
            pay[i] = (s << BSH) | (d & (BUCK_N - 1u));
            br[i]  = (b << 16) | r;
        }
    }
    __syncthreads();
    for (int i = t; i < NBUCK; i += FS_T) {
        unsigned c = hist[i];
        rbase[i] = c ? ((unsigned)i * BCAP + atomicAdd(&gcur[i], c)) : 0u;
    }
    __syncthreads();
#pragma unroll
    for (int i = 0; i < FS_EPT; ++i) {
        if (br[i] != 0xFFFFFFFFu) {
            unsigned bb = br[i] >> 16;
            unsigned idx = rbase[bb] + (br[i] & 0xFFFFu);
            if (idx < (bb + 1u) * BCAP) stage[idx] = pay[i];   // safety clamp
        }
    }
}

// Exclusive scan of 196 bucket counts -> bucket bases; total -> rowptr[N].
__global__ __launch_bounds__(256) void scan_buckets_kernel(
        const unsigned* __restrict__ gcur, unsigned* __restrict__ bbase,
        unsigned* __restrict__ rowptr) {
    __shared__ unsigned s[256];
    int t = threadIdx.x;
    unsigned v = (t < NBUCK) ? gcur[t] : 0u;
    s[t] = v;
    __syncthreads();
    for (int off = 1; off < 256; off <<= 1) {
        unsigned u = (t >= off) ? s[t - off] : 0u;
        __syncthreads();
        s[t] += u;
        __syncthreads();
    }
    if (t < NBUCK) bbase[t] = s[t] - v;
    if (t == 255) rowptr[N_NODES] = s[255];
}

// One block per bucket: degree histogram + local scan in LDS; writes rowptr,
// inv (coalesced), assembles csr slice in LDS, copies out coalesced.
// Replaces deg_count + memset + 3-phase global scan of R6.
__global__ __launch_bounds__(256) void fill_final_kernel(
        const unsigned* __restrict__ gcur, const unsigned* __restrict__ bbase,
        const unsigned* __restrict__ stage, unsigned* __restrict__ rowptr,
        float* __restrict__ inv, unsigned* __restrict__ csr_src) {
    __shared__ unsigned cur[BUCK_N];
    __shared__ unsigned ps[256];
    __shared__ unsigned buf[BCAP];
    int b = blockIdx.x, t = threadIdx.x;
    int lo = b << BSH;
    int nn = min(BUCK_N, N_NODES - lo);
    unsigned c = min(gcur[b], (unsigned)BCAP);
    unsigned base = bbase[b];
    const unsigned* st = stage + (size_t)b * BCAP;
    for (int i = t; i < BUCK_N; i += 256) cur[i] = 0u;
    __syncthreads();
    for (int i = t; i < (int)c; i += 256) atomicAdd(&cur[st[i] & (BUCK_N - 1u)], 1u);
    __syncthreads();
    unsigned d0 = cur[2 * t], d1 = cur[2 * t + 1];
    ps[t] = d0 + d1;
    __syncthreads();
    for (int off = 1; off < 256; off <<= 1) {
        unsigned u = (t >= off) ? ps[t - off] : 0u;
        __syncthreads();
        ps[t] += u;
        __syncthreads();
    }
    unsigned o0 = (t > 0) ? ps[t - 1] : 0u;   // exclusive offsets
    unsigned o1 = o0 + d0;
    if (2 * t < nn) {
        rowptr[lo + 2 * t] = base + o0;
        inv[lo + 2 * t] = rsqrtf((float)(d0 + 1u));
    }
    if (2 * t + 1 < nn) {
        rowptr[lo + 2 * t + 1] = base + o1;
        inv[lo + 2 * t + 1] = rsqrtf((float)(d1 + 1u));
    }
    __syncthreads();
    cur[2 * t] = o0; cur[2 * t + 1] = o1;
    __syncthreads();
    for (int i = t; i < (int)c; i += 256) {
        unsigned v = st[i];
        unsigned pos = atomicAdd(&cur[v & (BUCK_N - 1u)], 1u);
        buf[pos] = v >> BSH;
    }
    __syncthreads();
    for (int i = t; i < (int)c; i += 256) csr_src[base + i] = buf[i];
}

// -------------------------------------------------- GEMM (X@W)*inv -> bf16 --
// X: fp32 [n,K] (BF=false) or bf16 [n,64] (BF=true). W fp32 [K,64].
// out = bf16 [n,64]. Tile 64x64, 4x4 per thread, fp32 accumulate.
template <int K, bool BF>
__global__ __launch_bounds__(256) void gemm_scale_kernel(
        const void* __restrict__ Xv, const float* __restrict__ W,
        const float* __restrict__ inv, unsigned short* __restrict__ out, int n) {
    constexpr int C = 64;
    __shared__ float Ws[K * C];
    __shared__ float Xs[64][68];
    int t = threadIdx.x;
    int n0 = blockIdx.x * 64;
    for (int i = t; i < K * C / 4; i += 256)
        ((float4*)Ws)[i] = ((const float4*)W)[i];
    int cg = t & 15;
    int rg = t >> 4;
    float4 a0 = {0,0,0,0}, a1 = {0,0,0,0}, a2 = {0,0,0,0}, a3 = {0,0,0,0};
    for (int kb = 0; kb < K; kb += 64) {
        __syncthreads();
        if (BF) {
            const ushort4* Xb = (const ushort4*)Xv;   // row stride 16 ushort4
            for (int i = t; i < 1024; i += 256) {
                int row = i >> 4, kc = i & 15;
                int node = n0 + row;
                ushort4 v = {0,0,0,0};
                if (node < n) v = Xb[(size_t)node * 16 + kc];
                Xs[kc * 4 + 0][row] = bf2f(v.x);
                Xs[kc * 4 + 1][row] = bf2f(v.y);
                Xs[kc * 4 + 2][row] = bf2f(v.z);
                Xs[kc * 4 + 3][row] = bf2f(v.w);
            }
        } else {
            const float* Xf = (const float*)Xv;
            for (int i = t; i < 1024; i += 256) {
                int row = i >> 4, kc = i & 15;
                int node = n0 + row;
                float4 v = {0,0,0,0};
                if (node < n) v = *(const float4*)&Xf[(size_t)node * K + kb + kc * 4];
                Xs[kc * 4 + 0][row] = v.x;
                Xs[kc * 4 + 1][row] = v.y;
                Xs[kc * 4 + 2][row] = v.z;
                Xs[kc * 4 + 3][row] = v.w;
            }
        }
        __syncthreads();
#pragma unroll 8
        for (int k = 0; k < 64; ++k) {
            float4 b = *(const float4*)&Ws[(kb + k) * C + cg * 4];
            float4 a = *(const float4*)&Xs[k][rg * 4];
            a0.x += a.x * b.x; a0.y += a.x * b.y; a0.z += a.x * b.z; a0.w += a.x * b.w;
            a1.x += a.y * b.x; a1.y += a.y * b.y; a1.z += a.y * b.z; a1.w += a.y * b.w;
            a2.x += a.z * b.x; a2.y += a.z * b.y; a2.z += a.z * b.z; a2.w += a.z * b.w;
            a3.x += a.w * b.x; a3.y += a.w * b.y; a3.z += a.w * b.z; a3.w += a.w * b.w;
        }
    }
    float4 accs[4] = {a0, a1, a2, a3};
#pragma unroll
    for (int i = 0; i < 4; ++i) {
        int node = n0 + rg * 4 + i;
        if (node < n) {
            float s = inv[node];
            float4 r = accs[i];
            ushort4 o;
            o.x = f2bf(r.x * s); o.y = f2bf(r.y * s);
            o.z = f2bf(r.z * s); o.w = f2bf(r.w * s);
            *(ushort4*)&out[(size_t)node * 64 + cg * 4] = o;
        }
    }
}

// ---------------------------------------- fused gather-aggregate + epilogue -
// bf16 rows (128 B/edge gather, half of R6's 256 B). fp32 accumulate.
__global__ __launch_bounds__(256) void agg_fused_kernel(
        const unsigned* __restrict__ rowptr, const unsigned* __restrict__ csr_src,
        const unsigned short* __restrict__ hs, const float* __restrict__ inv,
        const float* __restrict__ bias, unsigned short* __restrict__ out) {
    int node = blockIdx.x * 4 + (threadIdx.x >> 6);
    int lane = threadIdx.x & 63;
    int q  = lane >> 4;
    int cl = lane & 15;
    unsigned beg = rowptr[node], end = rowptr[node + 1];
    float ax = 0.f, ay = 0.f, az = 0.f, aw = 0.f;
    for (unsigned j = beg + q; j < end; j += 4) {
        unsigned s = csr_src[j];
        ushort4 v = *(const ushort4*)&hs[(size_t)s * 64 + cl * 4];
        ax += bf2f(v.x); ay += bf2f(v.y); az += bf2f(v.z); aw += bf2f(v.w);
    }
    ax += __shfl_xor(ax, 16); ay += __shfl_xor(ay, 16);
    az += __shfl_xor(az, 16); aw += __shfl_xor(aw, 16);
    ax += __shfl_xor(ax, 32); ay += __shfl_xor(ay, 32);
    az += __shfl_xor(az, 32); aw += __shfl_xor(aw, 32);
    if (q == 0) {
        ushort4 sv = *(const ushort4*)&hs[(size_t)node * 64 + cl * 4];
        const float4 bv = *(const float4*)&bias[cl * 4];
        float s = inv[node];
        ushort4 o;
        o.x = f2bf(fmaxf(s * (ax + bf2f(sv.x)) + bv.x, 0.f));
        o.y = f2bf(fmaxf(s * (ay + bf2f(sv.y)) + bv.y, 0.f));
        o.z = f2bf(fmaxf(s * (az + bf2f(sv.z)) + bv.z, 0.f));
        o.w = f2bf(fmaxf(s * (aw + bf2f(sv.w)) + bv.w, 0.f));
        *(ushort4*)&out[(size_t)node * 64 + cl * 4] = o;
    }
}

// ---------------------------------------------- final classifier GEMM -------
// out[n,40] fp32 = H(bf16)[n,64] @ Wf[64,40] + bf.
__global__ __launch_bounds__(320) void final_gemm_kernel(
        const unsigned short* __restrict__ H, const float* __restrict__ Wf,
        const float* __restrict__ bfv, float* __restrict__ out, int n) {
    constexpr int CK = 64, J = 40;
    __shared__ float Ws[CK * J];
    __shared__ float Hs[CK][132];
    int t = threadIdx.x;
    int n0 = blockIdx.x * 128;
    for (int i = t; i < CK * J / 4; i += 320)
        ((float4*)Ws)[i] = ((const float4*)Wf)[i];
    for (int i = t; i < 128 * 16; i += 320) {
        int row = i >> 4, kc = i & 15;
        int node = n0 + row;
        ushort4 v = {0,0,0,0};
        if (node < n) v = *(const ushort4*)&H[(size_t)node * 64 + kc * 4];
        Hs[kc * 4 + 0][row] = bf2f(v.x);
        Hs[kc * 4 + 1][row] = bf2f(v.y);
        Hs[kc * 4 + 2][row] = bf2f(v.z);
        Hs[kc * 4 + 3][row] = bf2f(v.w);
    }
    __syncthreads();
    int cg = t % 10;
    int rg = t / 10;
    float4 a0 = {0,0,0,0}, a1 = {0,0,0,0}, a2 = {0,0,0,0}, a3 = {0,0,0,0};
#pragma unroll 8
    for (int k = 0; k < CK; ++k) {
        float4 b = *(const float4*)&Ws[k * J + cg * 4];
        float4 a = *(const float4*)&Hs[k][rg * 4];
        a0.x += a.x * b.x; a0.y += a.x * b.y; a0.z += a.x * b.z; a0.w += a.x * b.w;
        a1.x += a.y * b.x; a1.y += a.y * b.y; a1.z += a.y * b.z; a1.w += a.y * b.w;
        a2.x += a.z * b.x; a2.y += a.z * b.y; a2.z += a.z * b.z; a2.w += a.z * b.w;
        a3.x += a.w * b.x; a3.y += a.w * b.y; a3.z += a.w * b.z; a3.w += a.w * b.w;
    }
    float4 bv = *(const float4*)&bfv[cg * 4];
    float4 accs[4] = {a0, a1, a2, a3};
#pragma unroll
    for (int i = 0; i < 4; ++i) {
        int node = n0 + rg * 4 + i;
        if (node < n) {
            float4 r = accs[i];
            r.x += bv.x; r.y += bv.y; r.z += bv.z; r.w += bv.w;
            *(float4*)&out[(size_t)node * J + cg * 4] = r;
        }
    }
}

// ---------------------------------------------------------------- launch ----
extern "C" void kernel_launch(void* const* d_in, const int* in_sizes, int n_in,
                              void* d_out, int out_size, void* d_ws, size_t ws_size,
                              hipStream_t stream) {
    const float* x  = (const float*)d_in[0];
    const int*   ei = (const int*)d_in[1];
    const float* W1 = (const float*)d_in[2];
    const float* b1 = (const float*)d_in[3];
    const float* W2 = (const float*)d_in[4];
    const float* b2 = (const float*)d_in[5];
    const float* Wf = (const float*)d_in[6];
    const float* bf = (const float*)d_in[7];
    float* out = (float*)d_out;

    const int* src = ei;            // edge_index[0, :]
    const int* dst = ei + N_EDGES;  // edge_index[1, :]

    // Workspace layout (bytes):
    // rowptr: [0, 400064) | inv: [400064, 800064) | gcur: [800064, 800896)
    // bbase: [800896, 801792) | csr_src: [801792, 7201792)
    // A (bf16, 12.8MB): [7201792, 20001792) | B (bf16): [20001792, 32801792)
    // stage (7.23 MB) aliases A: dead before gemm1 writes A (stream-ordered).
    char* ws = (char*)d_ws;
    unsigned* rowptr  = (unsigned*)(ws + 0);
    float*    inv     = (float*)   (ws + 400064);
    unsigned* gcur    = (unsigned*)(ws + 800064);
    unsigned* bbase   = (unsigned*)(ws + 800896);
    unsigned* csr_src = (unsigned*)(ws + 801792);
    unsigned short* A = (unsigned short*)(ws + 7201792);
    unsigned short* B = (unsigned short*)(ws + 20001792);
    unsigned* stage   = (unsigned*)A;

    // ---- CSR build (per-call; no state survives between calls)
    bucket_init_kernel<<<1, 256, 0, stream>>>(gcur);
    fill_stage_kernel<<<FS_BLKS, FS_T, 0, stream>>>(src, dst, gcur, stage);
    scan_buckets_kernel<<<1, 256, 0, stream>>>(gcur, bbase, rowptr);
    fill_final_kernel<<<NBUCK, 256, 0, stream>>>(gcur, bbase, stage, rowptr, inv, csr_src);

    // ---- Layer 1
    gemm_scale_kernel<IN_C, false>
        <<<(N_NODES + 63) / 64, 256, 0, stream>>>(x, W1, inv, A, N_NODES);
    agg_fused_kernel<<<N_NODES / 4, 256, 0, stream>>>(rowptr, csr_src, A, inv, b1, B);

    // ---- Layer 2
    gemm_scale_kernel<HID_C, true>
        <<<(N_NODES + 63) / 64, 256, 0, stream>>>(B, W2, inv, A, N_NODES);
    agg_fused_kernel<<<N_NODES / 4, 256, 0, stream>>>(rowptr, csr_src, A, inv, b2, B);

    // ---- Classifier
    final_gemm_kernel<<<(N_NODES + 127) / 128, 320, 0, stream>>>(B, Wf, bf, out, N_NODES);
}

// Round 9
// 308.474 us; speedup vs baseline: 1.6707x; 1.0671x over previous
//
#include <hip/hip_runtime.h>

// Problem constants (fixed by the reference).
constexpr int N_NODES = 100000;
constexpr int N_EDGES = 1600000;
constexpr int IN_C  = 128;
constexpr int HID_C = 64;   // == OUT_C
constexpr int NUM_CLASSES = 40;

// Bucketed CSR build: 512-node buckets, fixed-capacity staging.
constexpr int BSH = 9;
constexpr int BUCK_N = 1 << BSH;                          // 512
constexpr int NBUCK = (N_NODES + BUCK_N - 1) >> BSH;      // 196
constexpr int BCAP = 9216;      // per-bucket cap; mean 8192, sd~90 (11σ margin)
constexpr int FS_EPT = 16;
constexpr int FS_T = 256;
constexpr int FS_CHUNK = FS_EPT * FS_T;                   // 4096
constexpr int FS_BLKS = (N_EDGES + FS_CHUNK - 1) / FS_CHUNK;  // 391

// bf16 storage helpers (fp32 math everywhere; bf16 only at rest).
__device__ __forceinline__ unsigned short f2bf(float f) {
    unsigned u = __float_as_uint(f);
    return (unsigned short)((u + 0x7FFFu + ((u >> 16) & 1u)) >> 16);   // RNE
}
__device__ __forceinline__ float bf2f(unsigned short h) {
    return __uint_as_float((unsigned)h << 16);
}

// ---------------------------------------------------------------- CSR -------
__global__ void bucket_init_kernel(unsigned* __restrict__ gcur) {
    if (threadIdx.x < NBUCK) gcur[threadIdx.x] = 0u;
}

// Group edges into fixed per-bucket staging regions, packed (src<<9)|dst_lo.
__global__ __launch_bounds__(FS_T) void fill_stage_kernel(
        const int* __restrict__ src, const int* __restrict__ dst,
        unsigned* __restrict__ gcur, unsigned* __restrict__ stage) {
    __shared__ unsigned hist[NBUCK];
    __shared__ unsigned rbase[NBUCK];
    int t = threadIdx.x;
    for (int i = t; i < NBUCK; i += FS_T) hist[i] = 0u;
    __syncthreads();
    int e0 = blockIdx.x * FS_CHUNK + t;
    unsigned pay[FS_EPT];
    unsigned br[FS_EPT];   // (bucket<<16)|rank
#pragma unroll
    for (int i = 0; i < FS_EPT; ++i) {
        int e = e0 + i * FS_T;
        br[i] = 0xFFFFFFFFu; pay[i] = 0u;
        if (e < N_EDGES) {
            unsigned d = (unsigned)dst[e];
            unsigned s = (unsigned)src[e];
            unsigned b = d >> BSH;
            unsigned r = atomicAdd(&hist[b], 1u);   // rank < 4096
            pay[i] = (s << BSH) | (d & (BUCK_N - 1u));
            br[i]  = (b << 16) | r;
        }
    }
    __syncthreads();
    for (int i = t; i < NBUCK; i += FS_T) {
        unsigned c = hist[i];
        rbase[i] = c ? ((unsigned)i * BCAP + atomicAdd(&gcur[i], c)) : 0u;
    }
    __syncthreads();
#pragma unroll
    for (int i = 0; i < FS_EPT; ++i) {
        if (br[i] != 0xFFFFFFFFu) {
            unsigned bb = br[i] >> 16;
            unsigned idx = rbase[bb] + (br[i] & 0xFFFFu);
            if (idx < (bb + 1u) * BCAP) stage[idx] = pay[i];   // safety clamp
        }
    }
}

// Exclusive scan of 196 bucket counts -> bucket bases; total -> rowptr[N].
__global__ __launch_bounds__(256) void scan_buckets_kernel(
        const unsigned* __restrict__ gcur, unsigned* __restrict__ bbase,
        unsigned* __restrict__ rowptr) {
    __shared__ unsigned s[256];
    int t = threadIdx.x;
    unsigned v = (t < NBUCK) ? gcur[t] : 0u;
    s[t] = v;
    __syncthreads();
    for (int off = 1; off < 256; off <<= 1) {
        unsigned u = (t >= off) ? s[t - off] : 0u;
        __syncthreads();
        s[t] += u;
        __syncthreads();
    }
    if (t < NBUCK) bbase[t] = s[t] - v;
    if (t == 255) rowptr[N_NODES] = s[255];
}

// One block per bucket: degree histogram + local scan in LDS; writes rowptr,
// inv (coalesced), assembles csr slice in LDS, copies out coalesced.
__global__ __launch_bounds__(256) void fill_final_kernel(
        const unsigned* __restrict__ gcur, const unsigned* __restrict__ bbase,
        const unsigned* __restrict__ stage, unsigned* __restrict__ rowptr,
        float* __restrict__ inv, unsigned* __restrict__ csr_src) {
    __shared__ unsigned cur[BUCK_N];
    __shared__ unsigned ps[256];
    __shared__ unsigned buf[BCAP];
    int b = blockIdx.x, t = threadIdx.x;
    int lo = b << BSH;
    int nn = min(BUCK_N, N_NODES - lo);
    unsigned c = min(gcur[b], (unsigned)BCAP);
    unsigned base = bbase[b];
    const unsigned* st = stage + (size_t)b * BCAP;
    for (int i = t; i < BUCK_N; i += 256) cur[i] = 0u;
    __syncthreads();
    for (int i = t; i < (int)c; i += 256) atomicAdd(&cur[st[i] & (BUCK_N - 1u)], 1u);
    __syncthreads();
    unsigned d0 = cur[2 * t], d1 = cur[2 * t + 1];
    ps[t] = d0 + d1;
    __syncthreads();
    for (int off = 1; off < 256; off <<= 1) {
        unsigned u = (t >= off) ? ps[t - off] : 0u;
        __syncthreads();
        ps[t] += u;
        __syncthreads();
    }
    unsigned o0 = (t > 0) ? ps[t - 1] : 0u;   // exclusive offsets
    unsigned o1 = o0 + d0;
    if (2 * t < nn) {
        rowptr[lo + 2 * t] = base + o0;
        inv[lo + 2 * t] = rsqrtf((float)(d0 + 1u));
    }
    if (2 * t + 1 < nn) {
        rowptr[lo + 2 * t + 1] = base + o1;
        inv[lo + 2 * t + 1] = rsqrtf((float)(d1 + 1u));
    }
    __syncthreads();
    cur[2 * t] = o0; cur[2 * t + 1] = o1;
    __syncthreads();
    for (int i = t; i < (int)c; i += 256) {
        unsigned v = st[i];
        unsigned pos = atomicAdd(&cur[v & (BUCK_N - 1u)], 1u);
        buf[pos] = v >> BSH;
    }
    __syncthreads();
    for (int i = t; i < (int)c; i += 256) csr_src[base + i] = buf[i];
}

// -------------------------------------------------- GEMM (X@W)*inv -> bf16 --
template <int K, bool BF>
__global__ __launch_bounds__(256) void gemm_scale_kernel(
        const void* __restrict__ Xv, const float* __restrict__ W,
        const float* __restrict__ inv, unsigned short* __restrict__ out, int n) {
    constexpr int C = 64;
    __shared__ float Ws[K * C];
    __shared__ float Xs[64][68];
    int t = threadIdx.x;
    int n0 = blockIdx.x * 64;
    for (int i = t; i < K * C / 4; i += 256)
        ((float4*)Ws)[i] = ((const float4*)W)[i];
    int cg = t & 15;
    int rg = t >> 4;
    float4 a0 = {0,0,0,0}, a1 = {0,0,0,0}, a2 = {0,0,0,0}, a3 = {0,0,0,0};
    for (int kb = 0; kb < K; kb += 64) {
        __syncthreads();
        if (BF) {
            const ushort4* Xb = (const ushort4*)Xv;   // row stride 16 ushort4
            for (int i = t; i < 1024; i += 256) {
                int row = i >> 4, kc = i & 15;
                int node = n0 + row;
                ushort4 v = {0,0,0,0};
                if (node < n) v = Xb[(size_t)node * 16 + kc];
                Xs[kc * 4 + 0][row] = bf2f(v.x);
                Xs[kc * 4 + 1][row] = bf2f(v.y);
                Xs[kc * 4 + 2][row] = bf2f(v.z);
                Xs[kc * 4 + 3][row] = bf2f(v.w);
            }
        } else {
            const float* Xf = (const float*)Xv;
            for (int i = t; i < 1024; i += 256) {
                int row = i >> 4, kc = i & 15;
                int node = n0 + row;
                float4 v = {0,0,0,0};
                if (node < n) v = *(const float4*)&Xf[(size_t)node * K + kb + kc * 4];
                Xs[kc * 4 + 0][row] = v.x;
                Xs[kc * 4 + 1][row] = v.y;
                Xs[kc * 4 + 2][row] = v.z;
                Xs[kc * 4 + 3][row] = v.w;
            }
        }
        __syncthreads();
#pragma unroll 8
        for (int k = 0; k < 64; ++k) {
            float4 b = *(const float4*)&Ws[(kb + k) * C + cg * 4];
            float4 a = *(const float4*)&Xs[k][rg * 4];
            a0.x += a.x * b.x; a0.y += a.x * b.y; a0.z += a.x * b.z; a0.w += a.x * b.w;
            a1.x += a.y * b.x; a1.y += a.y * b.y; a1.z += a.y * b.z; a1.w += a.y * b.w;
            a2.x += a.z * b.x; a2.y += a.z * b.y; a2.z += a.z * b.z; a2.w += a.z * b.w;
            a3.x += a.w * b.x; a3.y += a.w * b.y; a3.z += a.w * b.z; a3.w += a.w * b.w;
        }
    }
    float4 accs[4] = {a0, a1, a2, a3};
#pragma unroll
    for (int i = 0; i < 4; ++i) {
        int node = n0 + rg * 4 + i;
        if (node < n) {
            float s = inv[node];
            float4 r = accs[i];
            ushort4 o;
            o.x = f2bf(r.x * s); o.y = f2bf(r.y * s);
            o.z = f2bf(r.z * s); o.w = f2bf(r.w * s);
            *(ushort4*)&out[(size_t)node * 64 + cg * 4] = o;
        }
    }
}

// ---------------------------------------- fused gather-aggregate + epilogue -
// One wave per node; one coalesced csr load feeds 64 gathers via __shfl.
// GOTCHA (R8 failure): __shfl = ds_bpermute only carries values from
// exec-ACTIVE source lanes. The inner loop bound must be wave-uniform
// (it4 = navail rounded up to x4) so all 64 lanes stay active through every
// shfl; the gather itself is predicated on i < navail.
__global__ __launch_bounds__(256) void agg_fused_kernel(
        const unsigned* __restrict__ rowptr, const unsigned* __restrict__ csr_src,
        const unsigned short* __restrict__ hs, const float* __restrict__ inv,
        const float* __restrict__ bias, unsigned short* __restrict__ out) {
    int node = blockIdx.x * 4 + (threadIdx.x >> 6);
    int lane = threadIdx.x & 63;
    int q  = lane >> 4;
    int cl = lane & 15;
    unsigned beg = rowptr[node], end = rowptr[node + 1];
    float ax = 0.f, ay = 0.f, az = 0.f, aw = 0.f;
    for (unsigned base = beg; base < end; base += 64) {
        int navail = min((int)(end - base), 64);
        unsigned myidx = 0;
        if (lane < navail) myidx = csr_src[base + lane];
        int it4 = (navail + 3) & ~3;   // wave-uniform trip count
        for (int i = q; i < it4; i += 4) {
            unsigned s = __shfl(myidx, i);   // all 64 lanes active here
            if (i < navail) {
                ushort4 v = *(const ushort4*)&hs[(size_t)s * 64 + cl * 4];
                ax += bf2f(v.x); ay += bf2f(v.y); az += bf2f(v.z); aw += bf2f(v.w);
            }
        }
    }
    ax += __shfl_xor(ax, 16); ay += __shfl_xor(ay, 16);
    az += __shfl_xor(az, 16); aw += __shfl_xor(aw, 16);
    ax += __shfl_xor(ax, 32); ay += __shfl_xor(ay, 32);
    az += __shfl_xor(az, 32); aw += __shfl_xor(aw, 32);
    if (q == 0) {
        ushort4 sv = *(const ushort4*)&hs[(size_t)node * 64 + cl * 4];
        const float4 bv = *(const float4*)&bias[cl * 4];
        float s = inv[node];
        ushort4 o;
        o.x = f2bf(fmaxf(s * (ax + bf2f(sv.x)) + bv.x, 0.f));
        o.y = f2bf(fmaxf(s * (ay + bf2f(sv.y)) + bv.y, 0.f));
        o.z = f2bf(fmaxf(s * (az + bf2f(sv.z)) + bv.z, 0.f));
        o.w = f2bf(fmaxf(s * (aw + bf2f(sv.w)) + bv.w, 0.f));
        *(ushort4*)&out[(size_t)node * 64 + cl * 4] = o;
    }
}

// ---------------------------------------------- final classifier GEMM -------
__global__ __launch_bounds__(320) void final_gemm_kernel(
        const unsigned short* __restrict__ H, const float* __restrict__ Wf,
        const float* __restrict__ bfv, float* __restrict__ out, int n) {
    constexpr int CK = 64, J = 40;
    __shared__ float Ws[CK * J];
    __shared__ float Hs[CK][132];
    int t = threadIdx.x;
    int n0 = blockIdx.x * 128;
    for (int i = t; i < CK * J / 4; i += 320)
        ((float4*)Ws)[i] = ((const float4*)Wf)[i];
    for (int i = t; i < 128 * 16; i += 320) {
        int row = i >> 4, kc = i & 15;
        int node = n0 + row;
        ushort4 v = {0,0,0,0};
        if (node < n) v = *(const ushort4*)&H[(size_t)node * 64 + kc * 4];
        Hs[kc * 4 + 0][row] = bf2f(v.x);
        Hs[kc * 4 + 1][row] = bf2f(v.y);
        Hs[kc * 4 + 2][row] = bf2f(v.z);
        Hs[kc * 4 + 3][row] = bf2f(v.w);
    }
    __syncthreads();
    int cg = t % 10;
    int rg = t / 10;
    float4 a0 = {0,0,0,0}, a1 = {0,0,0,0}, a2 = {0,0,0,0}, a3 = {0,0,0,0};
#pragma unroll 8
    for (int k = 0; k < CK; ++k) {
        float4 b = *(const float4*)&Ws[k * J + cg * 4];
        float4 a = *(const float4*)&Hs[k][rg * 4];
        a0.x += a.x * b.x; a0.y += a.x * b.y; a0.z += a.x * b.z; a0.w += a.x * b.w;
        a1.x += a.y * b.x; a1.y += a.y * b.y; a1.z += a.y * b.z; a1.w += a.y * b.w;
        a2.x += a.z * b.x; a2.y += a.z * b.y; a2.z += a.z * b.z; a2.w += a.z * b.w;
        a3.x += a.w * b.x; a3.y += a.w * b.y; a3.z += a.w * b.z; a3.w += a.w * b.w;
    }
    float4 bv = *(const float4*)&bfv[cg * 4];
    float4 accs[4] = {a0, a1, a2, a3};
#pragma unroll
    for (int i = 0; i < 4; ++i) {
        int node = n0 + rg * 4 + i;
        if (node < n) {
            float4 r = accs[i];
            r.x += bv.x; r.y += bv.y; r.z += bv.z; r.w += bv.w;
            *(float4*)&out[(size_t)node * J + cg * 4] = r;
        }
    }
}

// ---------------------------------------------------------------- launch ----
extern "C" void kernel_launch(void* const* d_in, const int* in_sizes, int n_in,
                              void* d_out, int out_size, void* d_ws, size_t ws_size,
                              hipStream_t stream) {
    const float* x  = (const float*)d_in[0];
    const int*   ei = (const int*)d_in[1];
    const float* W1 = (const float*)d_in[2];
    const float* b1 = (const float*)d_in[3];
    const float* W2 = (const float*)d_in[4];
    const float* b2 = (const float*)d_in[5];
    const float* Wf = (const float*)d_in[6];
    const float* bf = (const float*)d_in[7];
    float* out = (float*)d_out;

    const int* src = ei;            // edge_index[0, :]
    const int* dst = ei + N_EDGES;  // edge_index[1, :]

    // Workspace layout (bytes):
    // rowptr: [0, 400064) | inv: [400064, 800064) | gcur: [800064, 800896)
    // bbase: [800896, 801792) | csr_src: [801792, 7201792)
    // A (bf16, 12.8MB): [7201792, 20001792) | B (bf16): [20001792, 32801792)
    // stage (7.23 MB) aliases A: dead before gemm1 writes A (stream-ordered).
    char* ws = (char*)d_ws;
    unsigned* rowptr  = (unsigned*)(ws + 0);
    float*    inv     = (float*)   (ws + 400064);
    unsigned* gcur    = (unsigned*)(ws + 800064);
    unsigned* bbase   = (unsigned*)(ws + 800896);
    unsigned* csr_src = (unsigned*)(ws + 801792);
    unsigned short* A = (unsigned short*)(ws + 7201792);
    unsigned short* B = (unsigned short*)(ws + 20001792);
    unsigned* stage   = (unsigned*)A;

    // ---- CSR build (per-call; no state survives between calls)
    bucket_init_kernel<<<1, 256, 0, stream>>>(gcur);
    fill_stage_kernel<<<FS_BLKS, FS_T, 0, stream>>>(src, dst, gcur, stage);
    scan_buckets_kernel<<<1, 256, 0, stream>>>(gcur, bbase, rowptr);
    fill_final_kernel<<<NBUCK, 256, 0, stream>>>(gcur, bbase, stage, rowptr, inv, csr_src);

    // ---- Layer 1
    gemm_scale_kernel<IN_C, false>
        <<<(N_NODES + 63) / 64, 256, 0, stream>>>(x, W1, inv, A, N_NODES);
    agg_fused_kernel<<<N_NODES / 4, 256, 0, stream>>>(rowptr, csr_src, A, inv, b1, B);

    // ---- Layer 2
    gemm_scale_kernel<HID_C, true>
        <<<(N_NODES + 63) / 64, 256, 0, stream>>>(B, W2, inv, A, N_NODES);
    agg_fused_kernel<<<N_NODES / 4, 256, 0, stream>>>(rowptr, csr_src, A, inv, b2, B);

    // ---- Classifier
    final_gemm_kernel<<<(N_NODES + 127) / 128, 320, 0, stream>>>(B, Wf, bf, out, N_NODES);
}

// Round 10
// 299.091 us; speedup vs baseline: 1.7231x; 1.0314x over previous
//
#include <hip/hip_runtime.h>

// Problem constants (fixed by the reference).
constexpr int N_NODES = 100000;
constexpr int N_EDGES = 1600000;
constexpr int IN_C  = 128;
constexpr int HID_C = 64;   // == OUT_C
constexpr int NUM_CLASSES = 40;

// Bucketed CSR build: 512-node buckets, fixed-capacity staging.
constexpr int BSH = 9;
constexpr int BUCK_N = 1 << BSH;                          // 512
constexpr int NBUCK = (N_NODES + BUCK_N - 1) >> BSH;      // 196
constexpr int BCAP = 9216;      // per-bucket cap; mean 8192, sd~90 (11σ margin)
constexpr int FS_EPT = 16;
constexpr int FS_T = 256;
constexpr int FS_CHUNK = FS_EPT * FS_T;                   // 4096
constexpr int FS_BLKS = (N_EDGES + FS_CHUNK - 1) / FS_CHUNK;  // 391

// bf16 storage helpers (fp32 math everywhere; bf16 only at rest).
__device__ __forceinline__ unsigned short f2bf(float f) {
    unsigned u = __float_as_uint(f);
    return (unsigned short)((u + 0x7FFFu + ((u >> 16) & 1u)) >> 16);   // RNE
}
__device__ __forceinline__ float bf2f(unsigned short h) {
    return __uint_as_float((unsigned)h << 16);
}

// ---------------------------------------------------------------- CSR -------
__global__ void bucket_init_kernel(unsigned* __restrict__ gcur) {
    if (threadIdx.x < NBUCK) gcur[threadIdx.x] = 0u;
}

// Group edges into fixed per-bucket staging regions, packed (src<<9)|dst_lo.
__global__ __launch_bounds__(FS_T) void fill_stage_kernel(
        const int* __restrict__ src, const int* __restrict__ dst,
        unsigned* __restrict__ gcur, unsigned* __restrict__ stage) {
    __shared__ unsigned hist[NBUCK];
    __shared__ unsigned rbase[NBUCK];
    int t = threadIdx.x;
    for (int i = t; i < NBUCK; i += FS_T) hist[i] = 0u;
    __syncthreads();
    int e0 = blockIdx.x * FS_CHUNK + t;
    unsigned pay[FS_EPT];
    unsigned br[FS_EPT];   // (bucket<<16)|rank
#pragma unroll
    for (int i = 0; i < FS_EPT; ++i) {
        int e = e0 + i * FS_T;
        br[i] = 0xFFFFFFFFu; pay[i] = 0u;
        if (e < N_EDGES) {
            unsigned d = (unsigned)dst[e];
            unsigned s = (unsigned)src[e];
            unsigned b = d >> BSH;
            unsigned r = atomicAdd(&hist[b], 1u);   // rank < 4096
            pay[i] = (s << BSH) | (d & (BUCK_N - 1u));
            br[i]  = (b << 16) | r;
        }
    }
    __syncthreads();
    for (int i = t; i < NBUCK; i += FS_T) {
        unsigned c = hist[i];
        rbase[i] = c ? ((unsigned)i * BCAP + atomicAdd(&gcur[i], c)) : 0u;
    }
    __syncthreads();
#pragma unroll
    for (int i = 0; i < FS_EPT; ++i) {
        if (br[i] != 0xFFFFFFFFu) {
            unsigned bb = br[i] >> 16;
            unsigned idx = rbase[bb] + (br[i] & 0xFFFFu);
            if (idx < (bb + 1u) * BCAP) stage[idx] = pay[i];   // safety clamp
        }
    }
}

// Exclusive scan of 196 bucket counts -> bucket bases; total -> rowptr[N].
__global__ __launch_bounds__(256) void scan_buckets_kernel(
        const unsigned* __restrict__ gcur, unsigned* __restrict__ bbase,
        unsigned* __restrict__ rowptr) {
    __shared__ unsigned s[256];
    int t = threadIdx.x;
    unsigned v = (t < NBUCK) ? gcur[t] : 0u;
    s[t] = v;
    __syncthreads();
    for (int off = 1; off < 256; off <<= 1) {
        unsigned u = (t >= off) ? s[t - off] : 0u;
        __syncthreads();
        s[t] += u;
        __syncthreads();
    }
    if (t < NBUCK) bbase[t] = s[t] - v;
    if (t == 255) rowptr[N_NODES] = s[255];
}

// One block per bucket: degree histogram + local scan in LDS; writes rowptr,
// inv (coalesced), assembles csr slice in LDS, copies out coalesced.
__global__ __launch_bounds__(256) void fill_final_kernel(
        const unsigned* __restrict__ gcur, const unsigned* __restrict__ bbase,
        const unsigned* __restrict__ stage, unsigned* __restrict__ rowptr,
        float* __restrict__ inv, unsigned* __restrict__ csr_src) {
    __shared__ unsigned cur[BUCK_N];
    __shared__ unsigned ps[256];
    __shared__ unsigned buf[BCAP];
    int b = blockIdx.x, t = threadIdx.x;
    int lo = b << BSH;
    int nn = min(BUCK_N, N_NODES - lo);
    unsigned c = min(gcur[b], (unsigned)BCAP);
    unsigned base = bbase[b];
    const unsigned* st = stage + (size_t)b * BCAP;
    for (int i = t; i < BUCK_N; i += 256) cur[i] = 0u;
    __syncthreads();
    for (int i = t; i < (int)c; i += 256) atomicAdd(&cur[st[i] & (BUCK_N - 1u)], 1u);
    __syncthreads();
    unsigned d0 = cur[2 * t], d1 = cur[2 * t + 1];
    ps[t] = d0 + d1;
    __syncthreads();
    for (int off = 1; off < 256; off <<= 1) {
        unsigned u = (t >= off) ? ps[t - off] : 0u;
        __syncthreads();
        ps[t] += u;
        __syncthreads();
    }
    unsigned o0 = (t > 0) ? ps[t - 1] : 0u;   // exclusive offsets
    unsigned o1 = o0 + d0;
    if (2 * t < nn) {
        rowptr[lo + 2 * t] = base + o0;
        inv[lo + 2 * t] = rsqrtf((float)(d0 + 1u));
    }
    if (2 * t + 1 < nn) {
        rowptr[lo + 2 * t + 1] = base + o1;
        inv[lo + 2 * t + 1] = rsqrtf((float)(d1 + 1u));
    }
    __syncthreads();
    cur[2 * t] = o0; cur[2 * t + 1] = o1;
    __syncthreads();
    for (int i = t; i < (int)c; i += 256) {
        unsigned v = st[i];
        unsigned pos = atomicAdd(&cur[v & (BUCK_N - 1u)], 1u);
        buf[pos] = v >> BSH;
    }
    __syncthreads();
    for (int i = t; i < (int)c; i += 256) csr_src[base + i] = buf[i];
}

// -------------------------------------------------- GEMM (X@W)*inv -> bf16 --
template <int K, bool BF>
__global__ __launch_bounds__(256) void gemm_scale_kernel(
        const void* __restrict__ Xv, const float* __restrict__ W,
        const float* __restrict__ inv, unsigned short* __restrict__ out, int n) {
    constexpr int C = 64;
    __shared__ float Ws[K * C];
    __shared__ float Xs[64][68];
    int t = threadIdx.x;
    int n0 = blockIdx.x * 64;
    for (int i = t; i < K * C / 4; i += 256)
        ((float4*)Ws)[i] = ((const float4*)W)[i];
    int cg = t & 15;
    int rg = t >> 4;
    float4 a0 = {0,0,0,0}, a1 = {0,0,0,0}, a2 = {0,0,0,0}, a3 = {0,0,0,0};
    for (int kb = 0; kb < K; kb += 64) {
        __syncthreads();
        if (BF) {
            const ushort4* Xb = (const ushort4*)Xv;   // row stride 16 ushort4
            for (int i = t; i < 1024; i += 256) {
                int row = i >> 4, kc = i & 15;
                int node = n0 + row;
                ushort4 v = {0,0,0,0};
                if (node < n) v = Xb[(size_t)node * 16 + kc];
                Xs[kc * 4 + 0][row] = bf2f(v.x);
                Xs[kc * 4 + 1][row] = bf2f(v.y);
                Xs[kc * 4 + 2][row] = bf2f(v.z);
                Xs[kc * 4 + 3][row] = bf2f(v.w);
            }
        } else {
            const float* Xf = (const float*)Xv;
            for (int i = t; i < 1024; i += 256) {
                int row = i >> 4, kc = i & 15;
                int node = n0 + row;
                float4 v = {0,0,0,0};
                if (node < n) v = *(const float4*)&Xf[(size_t)node * K + kb + kc * 4];
                Xs[kc * 4 + 0][row] = v.x;
                Xs[kc * 4 + 1][row] = v.y;
                Xs[kc * 4 + 2][row] = v.z;
                Xs[kc * 4 + 3][row] = v.w;
            }
        }
        __syncthreads();
#pragma unroll 8
        for (int k = 0; k < 64; ++k) {
            float4 b = *(const float4*)&Ws[(kb + k) * C + cg * 4];
            float4 a = *(const float4*)&Xs[k][rg * 4];
            a0.x += a.x * b.x; a0.y += a.x * b.y; a0.z += a.x * b.z; a0.w += a.x * b.w;
            a1.x += a.y * b.x; a1.y += a.y * b.y; a1.z += a.y * b.z; a1.w += a.y * b.w;
            a2.x += a.z * b.x; a2.y += a.z * b.y; a2.z += a.z * b.z; a2.w += a.z * b.w;
            a3.x += a.w * b.x; a3.y += a.w * b.y; a3.z += a.w * b.z; a3.w += a.w * b.w;
        }
    }
    float4 accs[4] = {a0, a1, a2, a3};
#pragma unroll
    for (int i = 0; i < 4; ++i) {
        int node = n0 + rg * 4 + i;
        if (node < n) {
            float s = inv[node];
            float4 r = accs[i];
            ushort4 o;
            o.x = f2bf(r.x * s); o.y = f2bf(r.y * s);
            o.z = f2bf(r.z * s); o.w = f2bf(r.w * s);
            *(ushort4*)&out[(size_t)node * 64 + cg * 4] = o;
        }
    }
}

// ---------------------------------------- fused gather-aggregate + epilogue -
// One wave per node; one coalesced csr load feeds 64 gathers via __shfl.
// R10: 8 octets x 8 lanes (was 4 quarters x 16): each lane covers 8 channels
// via one uint4 (8 bf16) load; 8 gathers in flight per wave-iteration (2x R9's
// MLP) at the same 2 VALU/channel unpack cost.
// GOTCHA (R8): __shfl = ds_bpermute only carries exec-ACTIVE source lanes ->
// loop bound must be wave-uniform (it8); gather predicated on i < navail.
__global__ __launch_bounds__(256) void agg_fused_kernel(
        const unsigned* __restrict__ rowptr, const unsigned* __restrict__ csr_src,
        const unsigned short* __restrict__ hs, const float* __restrict__ inv,
        const float* __restrict__ bias, unsigned short* __restrict__ out) {
    int node = blockIdx.x * 4 + (threadIdx.x >> 6);
    int lane = threadIdx.x & 63;
    int oct = lane >> 3;      // edge slot 0..7
    int cl  = lane & 7;       // channels cl*8 .. cl*8+7
    unsigned beg = rowptr[node], end = rowptr[node + 1];
    float a0 = 0.f, a1 = 0.f, a2 = 0.f, a3 = 0.f;
    float a4 = 0.f, a5 = 0.f, a6 = 0.f, a7 = 0.f;
    const uint4* hsrow = (const uint4*)hs;   // 16 B = 8 bf16; row = 8 uint4
    for (unsigned base = beg; base < end; base += 64) {
        int navail = min((int)(end - base), 64);
        unsigned myidx = 0;
        if (lane < navail) myidx = csr_src[base + lane];
        int it8 = (navail + 7) & ~7;   // wave-uniform trip count
        for (int i = oct; i < it8; i += 8) {
            unsigned s = __shfl(myidx, i);   // all 64 lanes active here
            if (i < navail) {
                uint4 v = hsrow[(size_t)s * 8 + cl];
                a0 += __uint_as_float(v.x << 16);
                a1 += __uint_as_float(v.x & 0xFFFF0000u);
                a2 += __uint_as_float(v.y << 16);
                a3 += __uint_as_float(v.y & 0xFFFF0000u);
                a4 += __uint_as_float(v.z << 16);
                a5 += __uint_as_float(v.z & 0xFFFF0000u);
                a6 += __uint_as_float(v.w << 16);
                a7 += __uint_as_float(v.w & 0xFFFF0000u);
            }
        }
    }
    a0 += __shfl_xor(a0, 8);  a1 += __shfl_xor(a1, 8);
    a2 += __shfl_xor(a2, 8);  a3 += __shfl_xor(a3, 8);
    a4 += __shfl_xor(a4, 8);  a5 += __shfl_xor(a5, 8);
    a6 += __shfl_xor(a6, 8);  a7 += __shfl_xor(a7, 8);
    a0 += __shfl_xor(a0, 16); a1 += __shfl_xor(a1, 16);
    a2 += __shfl_xor(a2, 16); a3 += __shfl_xor(a3, 16);
    a4 += __shfl_xor(a4, 16); a5 += __shfl_xor(a5, 16);
    a6 += __shfl_xor(a6, 16); a7 += __shfl_xor(a7, 16);
    a0 += __shfl_xor(a0, 32); a1 += __shfl_xor(a1, 32);
    a2 += __shfl_xor(a2, 32); a3 += __shfl_xor(a3, 32);
    a4 += __shfl_xor(a4, 32); a5 += __shfl_xor(a5, 32);
    a6 += __shfl_xor(a6, 32); a7 += __shfl_xor(a7, 32);
    if (oct == 0) {
        uint4 sv = hsrow[(size_t)node * 8 + cl];
        float4 bv0 = *(const float4*)&bias[cl * 8];
        float4 bv1 = *(const float4*)&bias[cl * 8 + 4];
        float s = inv[node];
        float r0 = fmaxf(s * (a0 + __uint_as_float(sv.x << 16))        + bv0.x, 0.f);
        float r1 = fmaxf(s * (a1 + __uint_as_float(sv.x & 0xFFFF0000u)) + bv0.y, 0.f);
        float r2 = fmaxf(s * (a2 + __uint_as_float(sv.y << 16))        + bv0.z, 0.f);
        float r3 = fmaxf(s * (a3 + __uint_as_float(sv.y & 0xFFFF0000u)) + bv0.w, 0.f);
        float r4 = fmaxf(s * (a4 + __uint_as_float(sv.z << 16))        + bv1.x, 0.f);
        float r5 = fmaxf(s * (a5 + __uint_as_float(sv.z & 0xFFFF0000u)) + bv1.y, 0.f);
        float r6 = fmaxf(s * (a6 + __uint_as_float(sv.w << 16))        + bv1.z, 0.f);
        float r7 = fmaxf(s * (a7 + __uint_as_float(sv.w & 0xFFFF0000u)) + bv1.w, 0.f);
        uint4 o;
        o.x = (unsigned)f2bf(r0) | ((unsigned)f2bf(r1) << 16);
        o.y = (unsigned)f2bf(r2) | ((unsigned)f2bf(r3) << 16);
        o.z = (unsigned)f2bf(r4) | ((unsigned)f2bf(r5) << 16);
        o.w = (unsigned)f2bf(r6) | ((unsigned)f2bf(r7) << 16);
        ((uint4*)out)[(size_t)node * 8 + cl] = o;
    }
}

// ---------------------------------------------- final classifier GEMM -------
__global__ __launch_bounds__(320) void final_gemm_kernel(
        const unsigned short* __restrict__ H, const float* __restrict__ Wf,
        const float* __restrict__ bfv, float* __restrict__ out, int n) {
    constexpr int CK = 64, J = 40;
    __shared__ float Ws[CK * J];
    __shared__ float Hs[CK][132];
    int t = threadIdx.x;
    int n0 = blockIdx.x * 128;
    for (int i = t; i < CK * J / 4; i += 320)
        ((float4*)Ws)[i] = ((const float4*)Wf)[i];
    for (int i = t; i < 128 * 16; i += 320) {
        int row = i >> 4, kc = i & 15;
        int node = n0 + row;
        ushort4 v = {0,0,0,0};
        if (node < n) v = *(const ushort4*)&H[(size_t)node * 64 + kc * 4];
        Hs[kc * 4 + 0][row] = bf2f(v.x);
        Hs[kc * 4 + 1][row] = bf2f(v.y);
        Hs[kc * 4 + 2][row] = bf2f(v.z);
        Hs[kc * 4 + 3][row] = bf2f(v.w);
    }
    __syncthreads();
    int cg = t % 10;
    int rg = t / 10;
    float4 a0 = {0,0,0,0}, a1 = {0,0,0,0}, a2 = {0,0,0,0}, a3 = {0,0,0,0};
#pragma unroll 8
    for (int k = 0; k < CK; ++k) {
        float4 b = *(const float4*)&Ws[k * J + cg * 4];
        float4 a = *(const float4*)&Hs[k][rg * 4];
        a0.x += a.x * b.x; a0.y += a.x * b.y; a0.z += a.x * b.z; a0.w += a.x * b.w;
        a1.x += a.y * b.x; a1.y += a.y * b.y; a1.z += a.y * b.z; a1.w += a.y * b.w;
        a2.x += a.z * b.x; a2.y += a.z * b.y; a2.z += a.z * b.z; a2.w += a.z * b.w;
        a3.x += a.w * b.x; a3.y += a.w * b.y; a3.z += a.w * b.z; a3.w += a.w * b.w;
    }
    float4 bv = *(const float4*)&bfv[cg * 4];
    float4 accs[4] = {a0, a1, a2, a3};
#pragma unroll
    for (int i = 0; i < 4; ++i) {
        int node = n0 + rg * 4 + i;
        if (node < n) {
            float4 r = accs[i];
            r.x += bv.x; r.y += bv.y; r.z += bv.z; r.w += bv.w;
            *(float4*)&out[(size_t)node * J + cg * 4] = r;
        }
    }
}

// ---------------------------------------------------------------- launch ----
extern "C" void kernel_launch(void* const* d_in, const int* in_sizes, int n_in,
                              void* d_out, int out_size, void* d_ws, size_t ws_size,
                              hipStream_t stream) {
    const float* x  = (const float*)d_in[0];
    const int*   ei = (const int*)d_in[1];
    const float* W1 = (const float*)d_in[2];
    const float* b1 = (const float*)d_in[3];
    const float* W2 = (const float*)d_in[4];
    const float* b2 = (const float*)d_in[5];
    const float* Wf = (const float*)d_in[6];
    const float* bf = (const float*)d_in[7];
    float* out = (float*)d_out;

    const int* src = ei;            // edge_index[0, :]
    const int* dst = ei + N_EDGES;  // edge_index[1, :]

    // Workspace layout (bytes):
    // rowptr: [0, 400064) | inv: [400064, 800064) | gcur: [800064, 800896)
    // bbase: [800896, 801792) | csr_src: [801792, 7201792)
    // A (bf16, 12.8MB): [7201792, 20001792) | B (bf16): [20001792, 32801792)
    // stage (7.23 MB) aliases A: dead before gemm1 writes A (stream-ordered).
    char* ws = (char*)d_ws;
    unsigned* rowptr  = (unsigned*)(ws + 0);
    float*    inv     = (float*)   (ws + 400064);
    unsigned* gcur    = (unsigned*)(ws + 800064);
    unsigned* bbase   = (unsigned*)(ws + 800896);
    unsigned* csr_src = (unsigned*)(ws + 801792);
    unsigned short* A = (unsigned short*)(ws + 7201792);
    unsigned short* B = (unsigned short*)(ws + 20001792);
    unsigned* stage   = (unsigned*)A;

    // ---- CSR build (per-call; no state survives between calls)
    bucket_init_kernel<<<1, 256, 0, stream>>>(gcur);
    fill_stage_kernel<<<FS_BLKS, FS_T, 0, stream>>>(src, dst, gcur, stage);
    scan_buckets_kernel<<<1, 256, 0, stream>>>(gcur, bbase, rowptr);
    fill_final_kernel<<<NBUCK, 256, 0, stream>>>(gcur, bbase, stage, rowptr, inv, csr_src);

    // ---- Layer 1
    gemm_scale_kernel<IN_C, false>
        <<<(N_NODES + 63) / 64, 256, 0, stream>>>(x, W1, inv, A, N_NODES);
    agg_fused_kernel<<<N_NODES / 4, 256, 0, stream>>>(rowptr, csr_src, A, inv, b1, B);

    // ---- Layer 2
    gemm_scale_kernel<HID_C, true>
        <<<(N_NODES + 63) / 64, 256, 0, stream>>>(B, W2, inv, A, N_NODES);
    agg_fused_kernel<<<N_NODES / 4, 256, 0, stream>>>(rowptr, csr_src, A, inv, b2, B);

    // ---- Classifier
    final_gemm_kernel<<<(N_NODES + 127) / 128, 320, 0, stream>>>(B, Wf, bf, out, N_NODES);
}

// Round 11
// 274.656 us; speedup vs baseline: 1.8764x; 1.0890x over previous
//
#include <hip/hip_runtime.h>

// Problem constants (fixed by the reference).
constexpr int N_NODES = 100000;
constexpr int N_EDGES = 1600000;
constexpr int IN_C  = 128;
constexpr int HID_C = 64;   // == OUT_C
constexpr int NUM_CLASSES = 40;

// Bucketed CSR build: 512-node buckets, fixed-capacity staging.
constexpr int BSH = 9;
constexpr int BUCK_N = 1 << BSH;                          // 512
constexpr int NBUCK = (N_NODES + BUCK_N - 1) >> BSH;      // 196
constexpr int BCAP = 9216;      // per-bucket cap; mean 8192, sd~90 (11σ margin)
constexpr int FS_EPT = 16;
constexpr int FS_T = 256;
constexpr int FS_CHUNK = FS_EPT * FS_T;                   // 4096
constexpr int FS_BLKS = (N_EDGES + FS_CHUNK - 1) / FS_CHUNK;  // 391

typedef __attribute__((ext_vector_type(8))) short bf16x8;
typedef __attribute__((ext_vector_type(4))) short short4v;
typedef __attribute__((ext_vector_type(4))) float f32x4;

// bf16 storage helpers (fp32 math everywhere; bf16 only at rest).
__device__ __forceinline__ unsigned short f2bf(float f) {
    unsigned u = __float_as_uint(f);
    return (unsigned short)((u + 0x7FFFu + ((u >> 16) & 1u)) >> 16);   // RNE
}
__device__ __forceinline__ float bf2f(unsigned short h) {
    return __uint_as_float((unsigned)h << 16);
}

// ---------------------------------------------------------------- CSR -------
__global__ void bucket_init_kernel(unsigned* __restrict__ gcur) {
    if (threadIdx.x < NBUCK) gcur[threadIdx.x] = 0u;
}

// Group edges into fixed per-bucket staging regions, packed (src<<9)|dst_lo.
__global__ __launch_bounds__(FS_T) void fill_stage_kernel(
        const int* __restrict__ src, const int* __restrict__ dst,
        unsigned* __restrict__ gcur, unsigned* __restrict__ stage) {
    __shared__ unsigned hist[NBUCK];
    __shared__ unsigned rbase[NBUCK];
    int t = threadIdx.x;
    for (int i = t; i < NBUCK; i += FS_T) hist[i] = 0u;
    __syncthreads();
    int e0 = blockIdx.x * FS_CHUNK + t;
    unsigned pay[FS_EPT];
    unsigned br[FS_EPT];   // (bucket<<16)|rank
#pragma unroll
    for (int i = 0; i < FS_EPT; ++i) {
        int e = e0 + i * FS_T;
        br[i] = 0xFFFFFFFFu; pay[i] = 0u;
        if (e < N_EDGES) {
            unsigned d = (unsigned)dst[e];
            unsigned s = (unsigned)src[e];
            unsigned b = d >> BSH;
            unsigned r = atomicAdd(&hist[b], 1u);   // rank < 4096
            pay[i] = (s << BSH) | (d & (BUCK_N - 1u));
            br[i]  = (b << 16) | r;
        }
    }
    __syncthreads();
    for (int i = t; i < NBUCK; i += FS_T) {
        unsigned c = hist[i];
        rbase[i] = c ? ((unsigned)i * BCAP + atomicAdd(&gcur[i], c)) : 0u;
    }
    __syncthreads();
#pragma unroll
    for (int i = 0; i < FS_EPT; ++i) {
        if (br[i] != 0xFFFFFFFFu) {
            unsigned bb = br[i] >> 16;
            unsigned idx = rbase[bb] + (br[i] & 0xFFFFu);
            if (idx < (bb + 1u) * BCAP) stage[idx] = pay[i];   // safety clamp
        }
    }
}

// Exclusive scan of 196 bucket counts -> bucket bases; total -> rowptr[N].
__global__ __launch_bounds__(256) void scan_buckets_kernel(
        const unsigned* __restrict__ gcur, unsigned* __restrict__ bbase,
        unsigned* __restrict__ rowptr) {
    __shared__ unsigned s[256];
    int t = threadIdx.x;
    unsigned v = (t < NBUCK) ? gcur[t] : 0u;
    s[t] = v;
    __syncthreads();
    for (int off = 1; off < 256; off <<= 1) {
        unsigned u = (t >= off) ? s[t - off] : 0u;
        __syncthreads();
        s[t] += u;
        __syncthreads();
    }
    if (t < NBUCK) bbase[t] = s[t] - v;
    if (t == 255) rowptr[N_NODES] = s[255];
}

// One block per bucket; 512 threads (R11: was 256 — these 196 blocks are
// latency-bound, so 8 waves/block for hiding). Histogram + scan in LDS;
// writes rowptr/inv coalesced; assembles csr slice in LDS; copies out.
__global__ __launch_bounds__(512) void fill_final_kernel(
        const unsigned* __restrict__ gcur, const unsigned* __restrict__ bbase,
        const unsigned* __restrict__ stage, unsigned* __restrict__ rowptr,
        float* __restrict__ inv, unsigned* __restrict__ csr_src) {
    __shared__ unsigned cur[BUCK_N];
    __shared__ unsigned ps[512];
    __shared__ unsigned buf[BCAP];
    int b = blockIdx.x, t = threadIdx.x;
    int lo = b << BSH;
    int nn = min(BUCK_N, N_NODES - lo);
    unsigned c = min(gcur[b], (unsigned)BCAP);
    unsigned base = bbase[b];
    const unsigned* st = stage + (size_t)b * BCAP;
    cur[t] = 0u;
    __syncthreads();
    for (int i = t; i < (int)c; i += 512) atomicAdd(&cur[st[i] & (BUCK_N - 1u)], 1u);
    __syncthreads();
    unsigned d = cur[t];
    ps[t] = d;
    __syncthreads();
    for (int off = 1; off < 512; off <<= 1) {
        unsigned u = (t >= off) ? ps[t - off] : 0u;
        __syncthreads();
        ps[t] += u;
        __syncthreads();
    }
    unsigned off0 = ps[t] - d;   // exclusive prefix
    if (t < nn) {
        rowptr[lo + t] = base + off0;
        inv[lo + t] = rsqrtf((float)(d + 1u));
    }
    __syncthreads();
    cur[t] = off0;
    __syncthreads();
    for (int i = t; i < (int)c; i += 512) {
        unsigned v = st[i];
        unsigned pos = atomicAdd(&cur[v & (BUCK_N - 1u)], 1u);
        buf[pos] = v >> BSH;
    }
    __syncthreads();
    for (int i = t; i < (int)c; i += 512) csr_src[base + i] = buf[i];
}

// ------------------------------------------- MFMA GEMM (X@W)*inv -> bf16 ----
// R11: replaces the VALU fp32 GEMM (~4096 FMA-cyc/wave) with bf16 MFMA.
// LDS: Asd[node][k] (k-contiguous, +8 pad -> 2-way-only conflicts),
//      Bsd[outch][k] = W^T (so B-frag is one ds_read_b128).
// Verified layouts (cdna_hip_programming §3): A[m=lane&15][k=quad*8+j],
// B[k=quad*8+j][n=lane&15], D: col=lane&15, row=quad*4+reg.
template <int K, bool BF>
__global__ __launch_bounds__(256) void gemm_mfma_kernel(
        const void* __restrict__ Xv, const float* __restrict__ W,
        const float* __restrict__ inv, unsigned short* __restrict__ out, int n) {
    __shared__ __align__(16) short Asd[64][K + 8];
    __shared__ __align__(16) short Bsd[64][K + 8];
    int t = threadIdx.x;
    int n0 = blockIdx.x * 64;
    // --- stage X -> Asd (node-major, k-contiguous bf16)
    if (BF) {
        const uint4* Xb = (const uint4*)Xv;   // bf16 row = 8 uint4
        for (int i = t; i < 64 * (K / 8); i += 256) {
            int row = i / (K / 8), seg = i % (K / 8);
            int node = n0 + row;
            uint4 v = {0, 0, 0, 0};
            if (node < n) v = Xb[(size_t)node * (K / 8) + seg];
            *(uint4*)&Asd[row][seg * 8] = v;
        }
    } else {
        const float* Xf = (const float*)Xv;
        for (int i = t; i < 64 * (K / 4); i += 256) {
            int row = i / (K / 4), seg = i % (K / 4);
            int node = n0 + row;
            float4 v = {0, 0, 0, 0};
            if (node < n) v = *(const float4*)&Xf[(size_t)node * K + seg * 4];
            short4v o;
            o.x = (short)f2bf(v.x); o.y = (short)f2bf(v.y);
            o.z = (short)f2bf(v.z); o.w = (short)f2bf(v.w);
            *(short4v*)&Asd[row][seg * 4] = o;
        }
    }
    // --- stage W^T -> Bsd (outch-major, k-contiguous bf16)
    for (int i = t; i < K * 16; i += 256) {
        int k = i >> 4, ng = i & 15;
        float4 v = *(const float4*)&W[(size_t)k * 64 + ng * 4];
        Bsd[ng * 4 + 0][k] = (short)f2bf(v.x);
        Bsd[ng * 4 + 1][k] = (short)f2bf(v.y);
        Bsd[ng * 4 + 2][k] = (short)f2bf(v.z);
        Bsd[ng * 4 + 3][k] = (short)f2bf(v.w);
    }
    __syncthreads();
    int wv = t >> 6, lane = t & 63;
    int m = lane & 15, quad = lane >> 4;
    int rowbase = wv * 16;
    f32x4 acc0 = {0,0,0,0}, acc1 = {0,0,0,0}, acc2 = {0,0,0,0}, acc3 = {0,0,0,0};
#pragma unroll
    for (int kb = 0; kb < K / 32; ++kb) {
        bf16x8 af = *(const bf16x8*)&Asd[rowbase + m][kb * 32 + quad * 8];
        bf16x8 b0 = *(const bf16x8*)&Bsd[ 0 + m][kb * 32 + quad * 8];
        bf16x8 b1 = *(const bf16x8*)&Bsd[16 + m][kb * 32 + quad * 8];
        bf16x8 b2 = *(const bf16x8*)&Bsd[32 + m][kb * 32 + quad * 8];
        bf16x8 b3 = *(const bf16x8*)&Bsd[48 + m][kb * 32 + quad * 8];
        acc0 = __builtin_amdgcn_mfma_f32_16x16x32_bf16(af, b0, acc0, 0, 0, 0);
        acc1 = __builtin_amdgcn_mfma_f32_16x16x32_bf16(af, b1, acc1, 0, 0, 0);
        acc2 = __builtin_amdgcn_mfma_f32_16x16x32_bf16(af, b2, acc2, 0, 0, 0);
        acc3 = __builtin_amdgcn_mfma_f32_16x16x32_bf16(af, b3, acc3, 0, 0, 0);
    }
    f32x4 accs[4] = {acc0, acc1, acc2, acc3};
#pragma unroll
    for (int r = 0; r < 4; ++r) {
        int node = n0 + rowbase + quad * 4 + r;
        if (node < n) {
            float sc = inv[node];
#pragma unroll
            for (int s = 0; s < 4; ++s)
                out[(size_t)node * 64 + s * 16 + m] = f2bf(accs[s][r] * sc);
        }
    }
}

// ---------------------------------------- fused gather-aggregate + epilogue -
// One wave per node; one coalesced csr load feeds 64 gathers via __shfl.
// 8 octets x 8 lanes; lane covers 8 channels (one uint4 = 8 bf16).
// GOTCHA (R8): __shfl = ds_bpermute only carries exec-ACTIVE source lanes ->
// loop bound must be wave-uniform (it8); gather predicated on i < navail.
__global__ __launch_bounds__(256) void agg_fused_kernel(
        const unsigned* __restrict__ rowptr, const unsigned* __restrict__ csr_src,
        const unsigned short* __restrict__ hs, const float* __restrict__ inv,
        const float* __restrict__ bias, unsigned short* __restrict__ out) {
    int node = blockIdx.x * 4 + (threadIdx.x >> 6);
    int lane = threadIdx.x & 63;
    int oct = lane >> 3;      // edge slot 0..7
    int cl  = lane & 7;       // channels cl*8 .. cl*8+7
    unsigned beg = rowptr[node], end = rowptr[node + 1];
    float a0 = 0.f, a1 = 0.f, a2 = 0.f, a3 = 0.f;
    float a4 = 0.f, a5 = 0.f, a6 = 0.f, a7 = 0.f;
    const uint4* hsrow = (const uint4*)hs;   // 16 B = 8 bf16; row = 8 uint4
    for (unsigned base = beg; base < end; base += 64) {
        int navail = min((int)(end - base), 64);
        unsigned myidx = 0;
        if (lane < navail) myidx = csr_src[base + lane];
        int it8 = (navail + 7) & ~7;   // wave-uniform trip count
        for (int i = oct; i < it8; i += 8) {
            unsigned s = __shfl(myidx, i);   // all 64 lanes active here
            if (i < navail) {
                uint4 v = hsrow[(size_t)s * 8 + cl];
                a0 += __uint_as_float(v.x << 16);
                a1 += __uint_as_float(v.x & 0xFFFF0000u);
                a2 += __uint_as_float(v.y << 16);
                a3 += __uint_as_float(v.y & 0xFFFF0000u);
                a4 += __uint_as_float(v.z << 16);
                a5 += __uint_as_float(v.z & 0xFFFF0000u);
                a6 += __uint_as_float(v.w << 16);
                a7 += __uint_as_float(v.w & 0xFFFF0000u);
            }
        }
    }
    a0 += __shfl_xor(a0, 8);  a1 += __shfl_xor(a1, 8);
    a2 += __shfl_xor(a2, 8);  a3 += __shfl_xor(a3, 8);
    a4 += __shfl_xor(a4, 8);  a5 += __shfl_xor(a5, 8);
    a6 += __shfl_xor(a6, 8);  a7 += __shfl_xor(a7, 8);
    a0 += __shfl_xor(a0, 16); a1 += __shfl_xor(a1, 16);
    a2 += __shfl_xor(a2, 16); a3 += __shfl_xor(a3, 16);
    a4 += __shfl_xor(a4, 16); a5 += __shfl_xor(a5, 16);
    a6 += __shfl_xor(a6, 16); a7 += __shfl_xor(a7, 16);
    a0 += __shfl_xor(a0, 32); a1 += __shfl_xor(a1, 32);
    a2 += __shfl_xor(a2, 32); a3 += __shfl_xor(a3, 32);
    a4 += __shfl_xor(a4, 32); a5 += __shfl_xor(a5, 32);
    a6 += __shfl_xor(a6, 32); a7 += __shfl_xor(a7, 32);
    if (oct == 0) {
        uint4 sv = hsrow[(size_t)node * 8 + cl];
        float4 bv0 = *(const float4*)&bias[cl * 8];
        float4 bv1 = *(const float4*)&bias[cl * 8 + 4];
        float s = inv[node];
        float r0 = fmaxf(s * (a0 + __uint_as_float(sv.x << 16))        + bv0.x, 0.f);
        float r1 = fmaxf(s * (a1 + __uint_as_float(sv.x & 0xFFFF0000u)) + bv0.y, 0.f);
        float r2 = fmaxf(s * (a2 + __uint_as_float(sv.y << 16))        + bv0.z, 0.f);
        float r3 = fmaxf(s * (a3 + __uint_as_float(sv.y & 0xFFFF0000u)) + bv0.w, 0.f);
        float r4 = fmaxf(s * (a4 + __uint_as_float(sv.z << 16))        + bv1.x, 0.f);
        float r5 = fmaxf(s * (a5 + __uint_as_float(sv.z & 0xFFFF0000u)) + bv1.y, 0.f);
        float r6 = fmaxf(s * (a6 + __uint_as_float(sv.w << 16))        + bv1.z, 0.f);
        float r7 = fmaxf(s * (a7 + __uint_as_float(sv.w & 0xFFFF0000u)) + bv1.w, 0.f);
        uint4 o;
        o.x = (unsigned)f2bf(r0) | ((unsigned)f2bf(r1) << 16);
        o.y = (unsigned)f2bf(r2) | ((unsigned)f2bf(r3) << 16);
        o.z = (unsigned)f2bf(r4) | ((unsigned)f2bf(r5) << 16);
        o.w = (unsigned)f2bf(r6) | ((unsigned)f2bf(r7) << 16);
        ((uint4*)out)[(size_t)node * 8 + cl] = o;
    }
}

// ---------------------------------------------- final classifier GEMM -------
__global__ __launch_bounds__(320) void final_gemm_kernel(
        const unsigned short* __restrict__ H, const float* __restrict__ Wf,
        const float* __restrict__ bfv, float* __restrict__ out, int n) {
    constexpr int CK = 64, J = 40;
    __shared__ float Ws[CK * J];
    __shared__ float Hs[CK][132];
    int t = threadIdx.x;
    int n0 = blockIdx.x * 128;
    for (int i = t; i < CK * J / 4; i += 320)
        ((float4*)Ws)[i] = ((const float4*)Wf)[i];
    for (int i = t; i < 128 * 16; i += 320) {
        int row = i >> 4, kc = i & 15;
        int node = n0 + row;
        ushort4 v = {0, 0, 0, 0};
        if (node < n) v = *(const ushort4*)&H[(size_t)node * 64 + kc * 4];
        Hs[kc * 4 + 0][row] = bf2f(v.x);
        Hs[kc * 4 + 1][row] = bf2f(v.y);
        Hs[kc * 4 + 2][row] = bf2f(v.z);
        Hs[kc * 4 + 3][row] = bf2f(v.w);
    }
    __syncthreads();
    int cg = t % 10;
    int rg = t / 10;
    float4 a0 = {0,0,0,0}, a1 = {0,0,0,0}, a2 = {0,0,0,0}, a3 = {0,0,0,0};
#pragma unroll 8
    for (int k = 0; k < CK; ++k) {
        float4 b = *(const float4*)&Ws[k * J + cg * 4];
        float4 a = *(const float4*)&Hs[k][rg * 4];
        a0.x += a.x * b.x; a0.y += a.x * b.y; a0.z += a.x * b.z; a0.w += a.x * b.w;
        a1.x += a.y * b.x; a1.y += a.y * b.y; a1.z += a.y * b.z; a1.w += a.y * b.w;
        a2.x += a.z * b.x; a2.y += a.z * b.y; a2.z += a.z * b.z; a2.w += a.z * b.w;
        a3.x += a.w * b.x; a3.y += a.w * b.y; a3.z += a.w * b.z; a3.w += a.w * b.w;
    }
    float4 bv = *(const float4*)&bfv[cg * 4];
    float4 accs[4] = {a0, a1, a2, a3};
#pragma unroll
    for (int i = 0; i < 4; ++i) {
        int node = n0 + rg * 4 + i;
        if (node < n) {
            float4 r = accs[i];
            r.x += bv.x; r.y += bv.y; r.z += bv.z; r.w += bv.w;
            *(float4*)&out[(size_t)node * J + cg * 4] = r;
        }
    }
}

// ---------------------------------------------------------------- launch ----
extern "C" void kernel_launch(void* const* d_in, const int* in_sizes, int n_in,
                              void* d_out, int out_size, void* d_ws, size_t ws_size,
                              hipStream_t stream) {
    const float* x  = (const float*)d_in[0];
    const int*   ei = (const int*)d_in[1];
    const float* W1 = (const float*)d_in[2];
    const float* b1 = (const float*)d_in[3];
    const float* W2 = (const float*)d_in[4];
    const float* b2 = (const float*)d_in[5];
    const float* Wf = (const float*)d_in[6];
    const float* bf = (const float*)d_in[7];
    float* out = (float*)d_out;

    const int* src = ei;            // edge_index[0, :]
    const int* dst = ei + N_EDGES;  // edge_index[1, :]

    // Workspace layout (bytes):
    // rowptr: [0, 400064) | inv: [400064, 800064) | gcur: [800064, 800896)
    // bbase: [800896, 801792) | csr_src: [801792, 7201792)
    // A (bf16, 12.8MB): [7201792, 20001792) | B (bf16): [20001792, 32801792)
    // stage (7.23 MB) aliases A: dead before gemm1 writes A (stream-ordered).
    char* ws = (char*)d_ws;
    unsigned* rowptr  = (unsigned*)(ws + 0);
    float*    inv     = (float*)   (ws + 400064);
    unsigned* gcur    = (unsigned*)(ws + 800064);
    unsigned* bbase   = (unsigned*)(ws + 800896);
    unsigned* csr_src = (unsigned*)(ws + 801792);
    unsigned short* A = (unsigned short*)(ws + 7201792);
    unsigned short* B = (unsigned short*)(ws + 20001792);
    unsigned* stage   = (unsigned*)A;

    // ---- CSR build (per-call; no state survives between calls)
    bucket_init_kernel<<<1, 256, 0, stream>>>(gcur);
    fill_stage_kernel<<<FS_BLKS, FS_T, 0, stream>>>(src, dst, gcur, stage);
    scan_buckets_kernel<<<1, 256, 0, stream>>>(gcur, bbase, rowptr);
    fill_final_kernel<<<NBUCK, 512, 0, stream>>>(gcur, bbase, stage, rowptr, inv, csr_src);

    // ---- Layer 1
    gemm_mfma_kernel<IN_C, false>
        <<<(N_NODES + 63) / 64, 256, 0, stream>>>(x, W1, inv, A, N_NODES);
    agg_fused_kernel<<<N_NODES / 4, 256, 0, stream>>>(rowptr, csr_src, A, inv, b1, B);

    // ---- Layer 2
    gemm_mfma_kernel<HID_C, true>
        <<<(N_NODES + 63) / 64, 256, 0, stream>>>(B, W2, inv, A, N_NODES);
    agg_fused_kernel<<<N_NODES / 4, 256, 0, stream>>>(rowptr, csr_src, A, inv, b2, B);

    // ---- Classifier
    final_gemm_kernel<<<(N_NODES + 127) / 128, 320, 0, stream>>>(B, Wf, bf, out, N_NODES);
}